// Round 6
// baseline (1005.383 us; speedup 1.0000x reference)
//
#include <hip/hip_runtime.h>
#include <hip/hip_bf16.h>

namespace {

constexpr int NB = 8;
constexpr int NV = 20000;
constexpr int NC = 256;
constexpr int NK = 128;
constexpr float LMBDA = 100.0f;
constexpr int KSTEP = 32;
constexpr int CHUNKS = 16;      // v-chunks; chunk 0 gets 40 steps, rest 39

typedef __attribute__((ext_vector_type(8))) short bf16x8;
typedef __attribute__((ext_vector_type(4))) float f32x4;

__device__ __forceinline__ ushort f2bf(float x) {
  uint u = __float_as_uint(x);
  u += 0x7fffu + ((u >> 16) & 1u);
  return (ushort)(u >> 16);
}
__device__ __forceinline__ float bf2f(ushort h) { return __uint_as_float(((uint)h) << 16); }

// ---------------------------------------------------------------------------
// 1) Spectral projection via split-bf16 MFMA (hi*hi + hi*lo + lo*hi).
// ---------------------------------------------------------------------------
template <int MODE>
__global__ __launch_bounds__(512, 4) void proj_mfma(
    const float* __restrict__ Ex, const float* __restrict__ Fx,
    const float* __restrict__ Ey, const float* __restrict__ Fy,
    float* __restrict__ A, float* __restrict__ Bm, float* __restrict__ P)
{
  const int chunk = blockIdx.x;            // 0..15
  const int ct    = blockIdx.y;            // 0..1 (c half)
  const int bs    = blockIdx.z;            // b*2+side
  const int b     = bs >> 1;
  const int side  = bs & 1;
  const float* __restrict__ E = (side ? Ey : Ex) + (size_t)b * NK * NV;
  const float* __restrict__ F = (side ? Fy : Fx) + (size_t)b * NV * NC;
  float* __restrict__ Out = (side ? Bm : A) + (size_t)b * NK * NC;
  const int cb = ct * 128;

  const int start = chunk * 39 + (chunk > 0 ? 1 : 0);
  const int nsteps = 39 + (chunk == 0 ? 1 : 0);
  const int v0 = start * KSTEP;

  __shared__ __align__(16) ushort AH[2][8][64][8];
  __shared__ __align__(16) ushort BH[2][8][64][8];

  const int tid  = threadIdx.x;
  const int lane = tid & 63;
  const int w    = tid >> 6;
  const int wm   = w >> 2;       // 0..1 (64-row group)
  const int wn   = w & 3;        // 0..3 (32-col group)
  const int lrow = lane >> 4;    // 0..3
  const int lcol = lane & 15;

  const int ek  = tid >> 2;
  const int evg = tid & 3;
  const int ef  = ek >> 4;
  const int entE = (((ek & 15) + evg * 4) & 15) + evg * 16;
  const float* Eptr = E + (size_t)ek * NV + v0 + evg * 8;

  const int fp  = tid & 15;
  const int fc0 = (tid >> 4) * 4;
  const int fcg = fc0 >> 4;
  const int fclow = fc0 & 15;
  const int fvg = fp >> 2;
  const int fsp = fp & 3;
  const float* Fptr = F + (size_t)(v0 + 2 * fp) * NC + cb + fc0;

  f32x4 acc[4][2];
#pragma unroll
  for (int fi = 0; fi < 4; fi++)
#pragma unroll
    for (int ni = 0; ni < 2; ni++) acc[fi][ni] = (f32x4)0.f;

  const int entA = (((lcol) + lrow * 4) & 15) + lrow * 16;

  float4 e0 = *(const float4*)(Eptr);
  float4 e1 = *(const float4*)(Eptr + 4);
  float4 f0 = *(const float4*)(Fptr);
  float4 f1 = *(const float4*)(Fptr + NC);

  for (int s = 0; s < nsteps; s++) {
    {
      const float v[8] = {e0.x, e0.y, e0.z, e0.w, e1.x, e1.y, e1.z, e1.w};
      uint hiw[4], low[4];
#pragma unroll
      for (int i = 0; i < 4; i++) {
        float a = v[2 * i], c = v[2 * i + 1];
        ushort ha = f2bf(a), hc = f2bf(c);
        hiw[i] = (uint)ha | ((uint)hc << 16);
        low[i] = (uint)f2bf(a - bf2f(ha)) | ((uint)f2bf(c - bf2f(hc)) << 16);
      }
      *(uint4*)&AH[0][ef][entE][0] = make_uint4(hiw[0], hiw[1], hiw[2], hiw[3]);
      *(uint4*)&AH[1][ef][entE][0] = make_uint4(low[0], low[1], low[2], low[3]);

      const float* fa = (const float*)&f0;
      const float* fb = (const float*)&f1;
#pragma unroll
      for (int j = 0; j < 4; j++) {
        int ent = ((fclow + j + fcg) & 15) + fvg * 16;
        float a = fa[j], c = fb[j];
        ushort ha = f2bf(a), hc = f2bf(c);
        *(uint*)&BH[0][fcg][ent][2 * fsp] = (uint)ha | ((uint)hc << 16);
        *(uint*)&BH[1][fcg][ent][2 * fsp] =
            (uint)f2bf(a - bf2f(ha)) | ((uint)f2bf(c - bf2f(hc)) << 16);
      }
    }
    __syncthreads();

    if (s + 1 < nsteps) {
      Eptr += KSTEP;
      Fptr += (size_t)KSTEP * NC;
      e0 = *(const float4*)(Eptr);
      e1 = *(const float4*)(Eptr + 4);
      f0 = *(const float4*)(Fptr);
      f1 = *(const float4*)(Fptr + NC);
    }

    {
      bf16x8 bHf[2], bLf[2];
#pragma unroll
      for (int ni = 0; ni < 2; ni++) {
        int cg = wn * 2 + ni;
        int entB = ((lcol + cg) & 15) + lrow * 16;
        bHf[ni] = *(const bf16x8*)&BH[0][cg][entB][0];
        bLf[ni] = *(const bf16x8*)&BH[1][cg][entB][0];
      }
#pragma unroll
      for (int fi = 0; fi < 4; fi++) {
        bf16x8 aH = *(const bf16x8*)&AH[0][wm * 4 + fi][entA][0];
        bf16x8 aL = *(const bf16x8*)&AH[1][wm * 4 + fi][entA][0];
#pragma unroll
        for (int ni = 0; ni < 2; ni++) {
          acc[fi][ni] = __builtin_amdgcn_mfma_f32_16x16x32_bf16(aH, bHf[ni], acc[fi][ni], 0, 0, 0);
          acc[fi][ni] = __builtin_amdgcn_mfma_f32_16x16x32_bf16(aH, bLf[ni], acc[fi][ni], 0, 0, 0);
          acc[fi][ni] = __builtin_amdgcn_mfma_f32_16x16x32_bf16(aL, bHf[ni], acc[fi][ni], 0, 0, 0);
        }
      }
    }
    __syncthreads();
  }

#pragma unroll
  for (int fi = 0; fi < 4; fi++) {
#pragma unroll
    for (int ni = 0; ni < 2; ni++) {
      const float* av = (const float*)&acc[fi][ni];
#pragma unroll
      for (int q = 0; q < 4; q++) {
        int row = wm * 64 + fi * 16 + lrow * 4 + q;
        int col = cb + wn * 32 + ni * 16 + lcol;
        if (MODE == 0) {
          P[(((size_t)chunk * 16 + bs) * NK + row) * NC + col] = av[q];
        } else {
          atomicAdd(&Out[(size_t)row * NC + col], av[q]);
        }
      }
    }
  }
}

__global__ __launch_bounds__(256) void reduce_kernel(
    const float* __restrict__ P, float* __restrict__ AB)
{
  const int g = blockIdx.x * 256 + threadIdx.x;
  const int bsi = g >> 13;
  const int rem4 = g & 8191;
  const int side = bsi & 1, b = bsi >> 1;
  float4 s = make_float4(0.f, 0.f, 0.f, 0.f);
#pragma unroll
  for (int ch = 0; ch < CHUNKS; ch++) {
    float4 v = *(const float4*)(P + (((size_t)ch * 16 + bsi) * 8192 + rem4) * 4);
    s.x += v.x; s.y += v.y; s.z += v.z; s.w += v.w;
  }
  *(float4*)(AB + ((size_t)side * 262144 + (size_t)b * 8192 * 4 + (size_t)rem4 * 4)) = s;
}

// ---------------------------------------------------------------------------
// 2) Gram
// ---------------------------------------------------------------------------
__global__ __launch_bounds__(256) void gram_kernel(
    const float* __restrict__ A, const float* __restrict__ Bm,
    float* __restrict__ AAt, float* __restrict__ BAt)
{
  const int i0 = blockIdx.x * 8;
  const int b  = blockIdx.y;
  __shared__ float Xi[16][260];
  const float* __restrict__ Ab = A  + (size_t)b * NK * NC;
  const float* __restrict__ Bb = Bm + (size_t)b * NK * NC;
  const int tid = threadIdx.x;
  for (int idx = tid; idx < 16 * 64; idx += 256) {
    int row = idx >> 6, c4 = idx & 63;
    const float* src = (row < 8) ? (Ab + (size_t)(i0 + row) * NC)
                                 : (Bb + (size_t)(i0 + row - 8) * NC);
    *(float4*)&Xi[row][c4 * 4] = *(const float4*)(src + c4 * 4);
  }
  __syncthreads();
  const int j = tid & 127;
  const int m = tid >> 7;
  const float* __restrict__ Arow = Ab + (size_t)j * NC;
  float accv[8];
#pragma unroll
  for (int i = 0; i < 8; i++) accv[i] = 0.f;
  for (int c4 = 0; c4 < 64; c4++) {
    float4 a4 = *(const float4*)(Arow + c4 * 4);
#pragma unroll
    for (int i = 0; i < 8; i++) {
      float4 x4 = *(const float4*)&Xi[m * 8 + i][c4 * 4];
      accv[i] = fmaf(x4.x, a4.x, accv[i]);
      accv[i] = fmaf(x4.y, a4.y, accv[i]);
      accv[i] = fmaf(x4.z, a4.z, accv[i]);
      accv[i] = fmaf(x4.w, a4.w, accv[i]);
    }
  }
  float* Outp = (m ? BAt : AAt) + ((size_t)b * NK + i0) * NK + j;
#pragma unroll
  for (int i = 0; i < 8; i++) Outp[(size_t)i * NK] = accv[i];
}

// ---------------------------------------------------------------------------
// 3) Mask D
// ---------------------------------------------------------------------------
__global__ __launch_bounds__(256) void mask_kernel(
    const float* __restrict__ evx, const float* __restrict__ evy,
    float* __restrict__ Dm)
{
  const int b = blockIdx.x;
  const int tid = threadIdx.x;
  __shared__ float red[256];
  __shared__ float t1x[128], t2x[128], t1y[128], t2y[128];
  float v = (tid < 128) ? evx[b * 128 + tid] : evy[b * 128 + (tid - 128)];
  red[tid] = v;
  __syncthreads();
  for (int sft = 128; sft > 0; sft >>= 1) {
    if (tid < sft) red[tid] = fmaxf(red[tid], red[tid + sft]);
    __syncthreads();
  }
  const float inv_scale = 1.0f / red[0];
  if (tid < 128) {
    float e = evx[b * 128 + tid] * inv_scale;
    float g = sqrtf(e);
    float d = 1.f / (g * g + 1.f);
    t1x[tid] = g * d;  t2x[tid] = d;
  } else {
    int i = tid - 128;
    float e = evy[b * 128 + i] * inv_scale;
    float g = sqrtf(e);
    float d = 1.f / (g * g + 1.f);
    t1y[i] = g * d;  t2y[i] = d;
  }
  __syncthreads();
  float* __restrict__ Db = Dm + (size_t)b * NK * NK;
  for (int idx = tid; idx < NK * NK; idx += 256) {
    int i = idx >> 7, jj = idx & 127;
    float re = t1y[i] - t1x[jj];
    float im = t2y[i] - t2x[jj];
    Db[idx] = re * re + im * im;
  }
}

// ---------------------------------------------------------------------------
// 4) Blocked Gauss-Jordan inversion, W=8 panels, REDUNDANT per-thread panel
//    inverse in registers. Only cross-thread dataflow: M reads -> barrier ->
//    M writes -> barrier. 16 panels x 2 barriers. Thread (r,h) exclusively
//    owns M[r][32h..32h+31].
// ---------------------------------------------------------------------------
__global__ __launch_bounds__(512) void invert_kernel(
    const float* __restrict__ AAt, float* __restrict__ Sinv)
{
  extern __shared__ float sh[];
  float* M = sh;                       // [128][132]
  float* R = sh + 128 * 132;           // [8][132] pivot-row snapshot
  const int b = blockIdx.x;
  const int tid = threadIdx.x;
  const float* __restrict__ Sb = AAt + (size_t)b * NK * NK;
  for (int idx = tid; idx < NK * NK; idx += 512) {
    M[(idx >> 7) * 132 + (idx & 127)] = Sb[idx];
  }
  __syncthreads();
  const int r = tid & 127;
  const int h = tid >> 7;
  const int c0 = h * 32;

  for (int p = 0; p < 16; p++) {
    const int J0 = p * 8;
    const bool inJ = (r >= J0) && (r < J0 + 8);

    // ---- phase A (reads M only): redundant G8 = inv(M[J,J]) in registers ---
    float g[8][8];
#pragma unroll
    for (int i = 0; i < 8; i++)
#pragma unroll
      for (int j = 0; j < 8; j++) g[i][j] = M[(J0 + i) * 132 + J0 + j];

#pragma unroll
    for (int j = 0; j < 8; j++) {
      const float invd = 1.f / g[j][j];
#pragma unroll
      for (int i = 0; i < 8; i++) {
        if (i == j) continue;
        const float f = g[i][j] * invd;
#pragma unroll
        for (int c = 0; c < 8; c++) {
          if (c == j) continue;
          g[i][c] = fmaf(-f, g[j][c], g[i][c]);
        }
        g[i][j] = -f;
      }
#pragma unroll
      for (int c = 0; c < 8; c++) {
        if (c == j) continue;
        g[j][c] *= invd;
      }
      g[j][j] = invd;
    }

    // coupling factors for my row
    float c8[8];
    if (inJ) {
      const int i0 = r - J0;
#pragma unroll
      for (int q = 0; q < 8; q++) c8[q] = ((i0 == q) ? 1.f : 0.f) - g[i0][q];
    } else {
      float mr8[8];
#pragma unroll
      for (int k = 0; k < 8; k++) mr8[k] = M[r * 132 + J0 + k];
#pragma unroll
      for (int q = 0; q < 8; q++) {
        float a = 0.f;
#pragma unroll
        for (int k = 0; k < 8; k++) a = fmaf(mr8[k], g[k][q], a);
        c8[q] = a;
      }
    }

    // R snapshot of pivot rows (reads M, writes R)
    if (inJ) {
      const int k = r - J0;
#pragma unroll
      for (int i = 0; i < 8; i++)
        *(float4*)&R[k * 132 + c0 + i * 4] = *(const float4*)&M[r * 132 + c0 + i * 4];
    }
    __syncthreads();

    // ---- phase C (writes M): Schur update on my exclusive slab ----
    float4 m[8];
#pragma unroll
    for (int i = 0; i < 8; i++) m[i] = *(const float4*)&M[r * 132 + c0 + i * 4];
#pragma unroll
    for (int k = 0; k < 8; k++) {
      const float f = c8[k];
#pragma unroll
      for (int i = 0; i < 8; i++) {
        float4 rv = *(const float4*)&R[k * 132 + c0 + i * 4];
        m[i].x = fmaf(-f, rv.x, m[i].x);
        m[i].y = fmaf(-f, rv.y, m[i].y);
        m[i].z = fmaf(-f, rv.z, m[i].z);
        m[i].w = fmaf(-f, rv.w, m[i].w);
      }
    }
    // panel columns (2 float4s inside slab hp) get the closed form
    if (h == (J0 >> 5)) {
      const int q4 = (J0 & 31) >> 2;     // first float4 index in slab
      float sp[8];
#pragma unroll
      for (int q = 0; q < 8; q++)
        sp[q] = -c8[q] + (((r - J0) == q) ? 1.f : 0.f);
      m[q4]     = make_float4(sp[0], sp[1], sp[2], sp[3]);
      m[q4 + 1] = make_float4(sp[4], sp[5], sp[6], sp[7]);
    }
#pragma unroll
    for (int i = 0; i < 8; i++) *(float4*)&M[r * 132 + c0 + i * 4] = m[i];
    __syncthreads();
  }

  float* __restrict__ Ob = Sinv + (size_t)b * NK * NK;
  for (int idx = tid; idx < NK * NK; idx += 512) {
    Ob[idx] = M[(idx >> 7) * 132 + (idx & 127)];
  }
}

// ---------------------------------------------------------------------------
// 4b) Newton-Schulz refinement: X <- X(2I - S*X). Squares the inverse
//     residual; polishes fp error and rescues a mildly-wrong Sinv.
// ---------------------------------------------------------------------------
__global__ __launch_bounds__(256) void ns_kernel(
    const float* __restrict__ AAt, float* __restrict__ Sinv)
{
  extern __shared__ float sh[];
  float* S_ = sh;               // [128][132], later holds W = 2I - S*X
  float* X_ = sh + 128 * 132;   // [128][132]
  const int b = blockIdx.x;
  const int tid = threadIdx.x;
  const float* __restrict__ Sg = AAt  + (size_t)b * NK * NK;
  float* __restrict__ Xg       = Sinv + (size_t)b * NK * NK;
  for (int idx = tid; idx < NK * NK; idx += 256) {
    int rr = idx >> 7, cc = idx & 127;
    S_[rr * 132 + cc] = Sg[idx];
    X_[rr * 132 + cc] = Xg[idx];
  }
  __syncthreads();
  const int i0 = (tid >> 4) * 8;
  const int j0 = (tid & 15) * 8;
  float w[8][8];
#pragma unroll
  for (int u = 0; u < 8; u++)
#pragma unroll
    for (int v = 0; v < 8; v++) w[u][v] = 0.f;
  for (int c = 0; c < NK; c++) {
    float sv[8], xv[8];
#pragma unroll
    for (int u = 0; u < 8; u++) sv[u] = S_[(i0 + u) * 132 + c];
#pragma unroll
    for (int v = 0; v < 8; v++) xv[v] = X_[c * 132 + j0 + v];
#pragma unroll
    for (int u = 0; u < 8; u++)
#pragma unroll
      for (int v = 0; v < 8; v++) w[u][v] = fmaf(sv[u], xv[v], w[u][v]);
  }
  __syncthreads();
#pragma unroll
  for (int u = 0; u < 8; u++)
#pragma unroll
    for (int v = 0; v < 8; v++) {
      float val = -w[u][v];
      if (i0 + u == j0 + v) val += 2.f;
      S_[(i0 + u) * 132 + j0 + v] = val;     // S_ now holds W
    }
  __syncthreads();
#pragma unroll
  for (int u = 0; u < 8; u++)
#pragma unroll
    for (int v = 0; v < 8; v++) w[u][v] = 0.f;
  for (int c = 0; c < NK; c++) {
    float xv[8], wv[8];
#pragma unroll
    for (int u = 0; u < 8; u++) xv[u] = X_[(i0 + u) * 132 + c];
#pragma unroll
    for (int v = 0; v < 8; v++) wv[v] = S_[c * 132 + j0 + v];
#pragma unroll
    for (int u = 0; u < 8; u++)
#pragma unroll
      for (int v = 0; v < 8; v++) w[u][v] = fmaf(xv[u], wv[v], w[u][v]);
  }
#pragma unroll
  for (int u = 0; u < 8; u++)
#pragma unroll
    for (int v = 0; v < 8; v++)
      Xg[(size_t)(i0 + u) * NK + j0 + v] = w[u][v];
}

// ---------------------------------------------------------------------------
// 5) Solve via Neumann fixed point (2 iterations).
// ---------------------------------------------------------------------------
__global__ __launch_bounds__(256) void solve_kernel(
    const float* __restrict__ Sinv, const float* __restrict__ BAt,
    const float* __restrict__ Dm, float* __restrict__ Cxy)
{
  extern __shared__ float sh[];
  float* SinvS = sh;               // [128][132]
  float* ZS    = sh + 128 * 132;   // [128][133]
  const int b = blockIdx.x;
  const int tid = threadIdx.x;
  const float* __restrict__ Sb = Sinv + (size_t)b * NK * NK;
  const float* __restrict__ Rb = BAt  + (size_t)b * NK * NK;
  const float* __restrict__ Db = Dm   + (size_t)b * NK * NK;
  for (int idx = tid; idx < NK * NK; idx += 256) {
    int r = idx >> 7, c = idx & 127;
    SinvS[r * 132 + c] = Sb[idx];
    ZS[r * 133 + c]    = Rb[idx];
  }
  __syncthreads();
  const int i0 = (tid >> 4) * 8;
  const int r0 = (tid & 15) * 8;
  float Y[8][8], X[8][8];
#pragma unroll
  for (int u = 0; u < 8; u++)
#pragma unroll
    for (int v = 0; v < 8; v++) Y[u][v] = 0.f;

  for (int c = 0; c < NK; c++) {
    float4 s0 = *(const float4*)&SinvS[c * 132 + r0];
    float4 s1 = *(const float4*)&SinvS[c * 132 + r0 + 4];
#pragma unroll
    for (int u = 0; u < 8; u++) {
      float z = ZS[(i0 + u) * 133 + c];
      Y[u][0] = fmaf(z, s0.x, Y[u][0]);
      Y[u][1] = fmaf(z, s0.y, Y[u][1]);
      Y[u][2] = fmaf(z, s0.z, Y[u][2]);
      Y[u][3] = fmaf(z, s0.w, Y[u][3]);
      Y[u][4] = fmaf(z, s1.x, Y[u][4]);
      Y[u][5] = fmaf(z, s1.y, Y[u][5]);
      Y[u][6] = fmaf(z, s1.z, Y[u][6]);
      Y[u][7] = fmaf(z, s1.w, Y[u][7]);
    }
  }
#pragma unroll
  for (int u = 0; u < 8; u++)
#pragma unroll
    for (int v = 0; v < 8; v++) X[u][v] = Y[u][v];

  for (int it = 0; it < 2; it++) {
    __syncthreads();
#pragma unroll
    for (int u = 0; u < 8; u++) {
      const float* drow = Db + (size_t)(i0 + u) * NK + r0;
      float* zrow = ZS + (i0 + u) * 133 + r0;
#pragma unroll
      for (int v = 0; v < 8; v++) zrow[v] = LMBDA * drow[v] * X[u][v];
    }
    __syncthreads();
#pragma unroll
    for (int u = 0; u < 8; u++)
#pragma unroll
      for (int v = 0; v < 8; v++) X[u][v] = Y[u][v];
    for (int c = 0; c < NK; c++) {
      float4 s0 = *(const float4*)&SinvS[c * 132 + r0];
      float4 s1 = *(const float4*)&SinvS[c * 132 + r0 + 4];
#pragma unroll
      for (int u = 0; u < 8; u++) {
        float z = ZS[(i0 + u) * 133 + c];
        X[u][0] = fmaf(-z, s0.x, X[u][0]);
        X[u][1] = fmaf(-z, s0.y, X[u][1]);
        X[u][2] = fmaf(-z, s0.z, X[u][2]);
        X[u][3] = fmaf(-z, s0.w, X[u][3]);
        X[u][4] = fmaf(-z, s1.x, X[u][4]);
        X[u][5] = fmaf(-z, s1.y, X[u][5]);
        X[u][6] = fmaf(-z, s1.z, X[u][6]);
        X[u][7] = fmaf(-z, s1.w, X[u][7]);
      }
    }
  }
  float* __restrict__ Ob = Cxy + ((size_t)b * NK + i0) * NK + r0;
#pragma unroll
  for (int u = 0; u < 8; u++) {
    float4 o0 = make_float4(X[u][0], X[u][1], X[u][2], X[u][3]);
    float4 o1 = make_float4(X[u][4], X[u][5], X[u][6], X[u][7]);
    *(float4*)(Ob + (size_t)u * NK)     = o0;
    *(float4*)(Ob + (size_t)u * NK + 4) = o1;
  }
}

} // anonymous namespace

extern "C" void kernel_launch(void* const* d_in, const int* in_sizes, int n_in,
                              void* d_out, int out_size, void* d_ws, size_t ws_size,
                              hipStream_t stream) {
  (void)in_sizes; (void)n_in; (void)out_size;
  const float* feat_x  = (const float*)d_in[0];
  const float* feat_y  = (const float*)d_in[1];
  const float* evals_x = (const float*)d_in[2];
  const float* evals_y = (const float*)d_in[3];
  const float* etx     = (const float*)d_in[4];
  const float* ety     = (const float*)d_in[5];
  float* out = (float*)d_out;
  float* ws  = (float*)d_ws;

  float* A    = ws;
  float* Bm   = ws + 262144;
  float* AAt  = ws + 524288;
  float* BAt  = ws + 655360;
  float* Dm   = ws + 786432;
  float* Sinv = ws + 917504;
  float* P    = ws + 1048576;

  const bool use_partial = ws_size >= (size_t)(1048576 + 8388608) * 4;

  constexpr int INV_LDS = (128 * 132 + 8 * 132) * 4;        // 71808 B
  constexpr int NS_LDS  = (2 * 128 * 132) * 4;              // 135168 B
  hipFuncSetAttribute((const void*)invert_kernel,
                      hipFuncAttributeMaxDynamicSharedMemorySize, INV_LDS);
  hipFuncSetAttribute((const void*)ns_kernel,
                      hipFuncAttributeMaxDynamicSharedMemorySize, NS_LDS);
  hipFuncSetAttribute((const void*)solve_kernel,
                      hipFuncAttributeMaxDynamicSharedMemorySize, (128 * 132 + 128 * 133) * 4);

  if (use_partial) {
    proj_mfma<0><<<dim3(CHUNKS, 2, 16), 512, 0, stream>>>(etx, feat_x, ety, feat_y, A, Bm, P);
    reduce_kernel<<<dim3(512), 256, 0, stream>>>(P, ws);
  } else {
    hipMemsetAsync(A, 0, (size_t)524288 * sizeof(float), stream);
    proj_mfma<1><<<dim3(CHUNKS, 2, 16), 512, 0, stream>>>(etx, feat_x, ety, feat_y, A, Bm, P);
  }
  gram_kernel<<<dim3(16, 8), 256, 0, stream>>>(A, Bm, AAt, BAt);
  mask_kernel<<<dim3(8), 256, 0, stream>>>(evals_x, evals_y, Dm);
  invert_kernel<<<dim3(8), 512, INV_LDS, stream>>>(AAt, Sinv);
  ns_kernel<<<dim3(8), 256, NS_LDS, stream>>>(AAt, Sinv);
  ns_kernel<<<dim3(8), 256, NS_LDS, stream>>>(AAt, Sinv);
  solve_kernel<<<dim3(8), 256, (128 * 132 + 128 * 133) * 4, stream>>>(Sinv, BAt, Dm, out);
}

// Round 7
// 1003.779 us; speedup vs baseline: 1.0016x; 1.0016x over previous
//
#include <hip/hip_runtime.h>
#include <hip/hip_bf16.h>

namespace {

constexpr int NB = 8;
constexpr int NV = 20000;
constexpr int NC = 256;
constexpr int NK = 128;
constexpr float LMBDA = 100.0f;
constexpr int KSTEP = 32;
constexpr int CHUNKS = 16;      // v-chunks; chunk 0 gets 40 steps, rest 39

typedef __attribute__((ext_vector_type(8))) short bf16x8;
typedef __attribute__((ext_vector_type(4))) float f32x4;

__device__ __forceinline__ ushort f2bf(float x) {
  uint u = __float_as_uint(x);
  u += 0x7fffu + ((u >> 16) & 1u);
  return (ushort)(u >> 16);
}
__device__ __forceinline__ float bf2f(ushort h) { return __uint_as_float(((uint)h) << 16); }

// ---------------------------------------------------------------------------
// 1) Spectral projection via split-bf16 MFMA (hi*hi + hi*lo + lo*hi).
// ---------------------------------------------------------------------------
template <int MODE>
__global__ __launch_bounds__(512, 4) void proj_mfma(
    const float* __restrict__ Ex, const float* __restrict__ Fx,
    const float* __restrict__ Ey, const float* __restrict__ Fy,
    float* __restrict__ A, float* __restrict__ Bm, float* __restrict__ P)
{
  const int chunk = blockIdx.x;            // 0..15
  const int ct    = blockIdx.y;            // 0..1 (c half)
  const int bs    = blockIdx.z;            // b*2+side
  const int b     = bs >> 1;
  const int side  = bs & 1;
  const float* __restrict__ E = (side ? Ey : Ex) + (size_t)b * NK * NV;
  const float* __restrict__ F = (side ? Fy : Fx) + (size_t)b * NV * NC;
  float* __restrict__ Out = (side ? Bm : A) + (size_t)b * NK * NC;
  const int cb = ct * 128;

  const int start = chunk * 39 + (chunk > 0 ? 1 : 0);
  const int nsteps = 39 + (chunk == 0 ? 1 : 0);
  const int v0 = start * KSTEP;

  __shared__ __align__(16) ushort AH[2][8][64][8];
  __shared__ __align__(16) ushort BH[2][8][64][8];

  const int tid  = threadIdx.x;
  const int lane = tid & 63;
  const int w    = tid >> 6;
  const int wm   = w >> 2;       // 0..1 (64-row group)
  const int wn   = w & 3;        // 0..3 (32-col group)
  const int lrow = lane >> 4;    // 0..3
  const int lcol = lane & 15;

  const int ek  = tid >> 2;
  const int evg = tid & 3;
  const int ef  = ek >> 4;
  const int entE = (((ek & 15) + evg * 4) & 15) + evg * 16;
  const float* Eptr = E + (size_t)ek * NV + v0 + evg * 8;

  const int fp  = tid & 15;
  const int fc0 = (tid >> 4) * 4;
  const int fcg = fc0 >> 4;
  const int fclow = fc0 & 15;
  const int fvg = fp >> 2;
  const int fsp = fp & 3;
  const float* Fptr = F + (size_t)(v0 + 2 * fp) * NC + cb + fc0;

  f32x4 acc[4][2];
#pragma unroll
  for (int fi = 0; fi < 4; fi++)
#pragma unroll
    for (int ni = 0; ni < 2; ni++) acc[fi][ni] = (f32x4)0.f;

  const int entA = (((lcol) + lrow * 4) & 15) + lrow * 16;

  float4 e0 = *(const float4*)(Eptr);
  float4 e1 = *(const float4*)(Eptr + 4);
  float4 f0 = *(const float4*)(Fptr);
  float4 f1 = *(const float4*)(Fptr + NC);

  for (int s = 0; s < nsteps; s++) {
    {
      const float v[8] = {e0.x, e0.y, e0.z, e0.w, e1.x, e1.y, e1.z, e1.w};
      uint hiw[4], low[4];
#pragma unroll
      for (int i = 0; i < 4; i++) {
        float a = v[2 * i], c = v[2 * i + 1];
        ushort ha = f2bf(a), hc = f2bf(c);
        hiw[i] = (uint)ha | ((uint)hc << 16);
        low[i] = (uint)f2bf(a - bf2f(ha)) | ((uint)f2bf(c - bf2f(hc)) << 16);
      }
      *(uint4*)&AH[0][ef][entE][0] = make_uint4(hiw[0], hiw[1], hiw[2], hiw[3]);
      *(uint4*)&AH[1][ef][entE][0] = make_uint4(low[0], low[1], low[2], low[3]);

      const float* fa = (const float*)&f0;
      const float* fb = (const float*)&f1;
#pragma unroll
      for (int j = 0; j < 4; j++) {
        int ent = ((fclow + j + fcg) & 15) + fvg * 16;
        float a = fa[j], c = fb[j];
        ushort ha = f2bf(a), hc = f2bf(c);
        *(uint*)&BH[0][fcg][ent][2 * fsp] = (uint)ha | ((uint)hc << 16);
        *(uint*)&BH[1][fcg][ent][2 * fsp] =
            (uint)f2bf(a - bf2f(ha)) | ((uint)f2bf(c - bf2f(hc)) << 16);
      }
    }
    __syncthreads();

    if (s + 1 < nsteps) {
      Eptr += KSTEP;
      Fptr += (size_t)KSTEP * NC;
      e0 = *(const float4*)(Eptr);
      e1 = *(const float4*)(Eptr + 4);
      f0 = *(const float4*)(Fptr);
      f1 = *(const float4*)(Fptr + NC);
    }

    {
      bf16x8 bHf[2], bLf[2];
#pragma unroll
      for (int ni = 0; ni < 2; ni++) {
        int cg = wn * 2 + ni;
        int entB = ((lcol + cg) & 15) + lrow * 16;
        bHf[ni] = *(const bf16x8*)&BH[0][cg][entB][0];
        bLf[ni] = *(const bf16x8*)&BH[1][cg][entB][0];
      }
#pragma unroll
      for (int fi = 0; fi < 4; fi++) {
        bf16x8 aH = *(const bf16x8*)&AH[0][wm * 4 + fi][entA][0];
        bf16x8 aL = *(const bf16x8*)&AH[1][wm * 4 + fi][entA][0];
#pragma unroll
        for (int ni = 0; ni < 2; ni++) {
          acc[fi][ni] = __builtin_amdgcn_mfma_f32_16x16x32_bf16(aH, bHf[ni], acc[fi][ni], 0, 0, 0);
          acc[fi][ni] = __builtin_amdgcn_mfma_f32_16x16x32_bf16(aH, bLf[ni], acc[fi][ni], 0, 0, 0);
          acc[fi][ni] = __builtin_amdgcn_mfma_f32_16x16x32_bf16(aL, bHf[ni], acc[fi][ni], 0, 0, 0);
        }
      }
    }
    __syncthreads();
  }

#pragma unroll
  for (int fi = 0; fi < 4; fi++) {
#pragma unroll
    for (int ni = 0; ni < 2; ni++) {
      const float* av = (const float*)&acc[fi][ni];
#pragma unroll
      for (int q = 0; q < 4; q++) {
        int row = wm * 64 + fi * 16 + lrow * 4 + q;
        int col = cb + wn * 32 + ni * 16 + lcol;
        if (MODE == 0) {
          P[(((size_t)chunk * 16 + bs) * NK + row) * NC + col] = av[q];
        } else {
          atomicAdd(&Out[(size_t)row * NC + col], av[q]);
        }
      }
    }
  }
}

__global__ __launch_bounds__(256) void reduce_kernel(
    const float* __restrict__ P, float* __restrict__ AB)
{
  const int g = blockIdx.x * 256 + threadIdx.x;
  const int bsi = g >> 13;
  const int rem4 = g & 8191;
  const int side = bsi & 1, b = bsi >> 1;
  float4 s = make_float4(0.f, 0.f, 0.f, 0.f);
#pragma unroll
  for (int ch = 0; ch < CHUNKS; ch++) {
    float4 v = *(const float4*)(P + (((size_t)ch * 16 + bsi) * 8192 + rem4) * 4);
    s.x += v.x; s.y += v.y; s.z += v.z; s.w += v.w;
  }
  *(float4*)(AB + ((size_t)side * 262144 + (size_t)b * 8192 * 4 + (size_t)rem4 * 4)) = s;
}

// ---------------------------------------------------------------------------
// 2) Gram
// ---------------------------------------------------------------------------
__global__ __launch_bounds__(256) void gram_kernel(
    const float* __restrict__ A, const float* __restrict__ Bm,
    float* __restrict__ AAt, float* __restrict__ BAt)
{
  const int i0 = blockIdx.x * 8;
  const int b  = blockIdx.y;
  __shared__ float Xi[16][260];
  const float* __restrict__ Ab = A  + (size_t)b * NK * NC;
  const float* __restrict__ Bb = Bm + (size_t)b * NK * NC;
  const int tid = threadIdx.x;
  for (int idx = tid; idx < 16 * 64; idx += 256) {
    int row = idx >> 6, c4 = idx & 63;
    const float* src = (row < 8) ? (Ab + (size_t)(i0 + row) * NC)
                                 : (Bb + (size_t)(i0 + row - 8) * NC);
    *(float4*)&Xi[row][c4 * 4] = *(const float4*)(src + c4 * 4);
  }
  __syncthreads();
  const int j = tid & 127;
  const int m = tid >> 7;
  const float* __restrict__ Arow = Ab + (size_t)j * NC;
  float accv[8];
#pragma unroll
  for (int i = 0; i < 8; i++) accv[i] = 0.f;
  for (int c4 = 0; c4 < 64; c4++) {
    float4 a4 = *(const float4*)(Arow + c4 * 4);
#pragma unroll
    for (int i = 0; i < 8; i++) {
      float4 x4 = *(const float4*)&Xi[m * 8 + i][c4 * 4];
      accv[i] = fmaf(x4.x, a4.x, accv[i]);
      accv[i] = fmaf(x4.y, a4.y, accv[i]);
      accv[i] = fmaf(x4.z, a4.z, accv[i]);
      accv[i] = fmaf(x4.w, a4.w, accv[i]);
    }
  }
  float* Outp = (m ? BAt : AAt) + ((size_t)b * NK + i0) * NK + j;
#pragma unroll
  for (int i = 0; i < 8; i++) Outp[(size_t)i * NK] = accv[i];
}

// ---------------------------------------------------------------------------
// 3) Mask D
// ---------------------------------------------------------------------------
__global__ __launch_bounds__(256) void mask_kernel(
    const float* __restrict__ evx, const float* __restrict__ evy,
    float* __restrict__ Dm)
{
  const int b = blockIdx.x;
  const int tid = threadIdx.x;
  __shared__ float red[256];
  __shared__ float t1x[128], t2x[128], t1y[128], t2y[128];
  float v = (tid < 128) ? evx[b * 128 + tid] : evy[b * 128 + (tid - 128)];
  red[tid] = v;
  __syncthreads();
  for (int sft = 128; sft > 0; sft >>= 1) {
    if (tid < sft) red[tid] = fmaxf(red[tid], red[tid + sft]);
    __syncthreads();
  }
  const float inv_scale = 1.0f / red[0];
  if (tid < 128) {
    float e = evx[b * 128 + tid] * inv_scale;
    float g = sqrtf(e);
    float d = 1.f / (g * g + 1.f);
    t1x[tid] = g * d;  t2x[tid] = d;
  } else {
    int i = tid - 128;
    float e = evy[b * 128 + i] * inv_scale;
    float g = sqrtf(e);
    float d = 1.f / (g * g + 1.f);
    t1y[i] = g * d;  t2y[i] = d;
  }
  __syncthreads();
  float* __restrict__ Db = Dm + (size_t)b * NK * NK;
  for (int idx = tid; idx < NK * NK; idx += 256) {
    int i = idx >> 7, jj = idx & 127;
    float re = t1y[i] - t1x[jj];
    float im = t2y[i] - t2x[jj];
    Db[idx] = re * re + im * im;
  }
}

// ---------------------------------------------------------------------------
// 4) Blocked Gauss-Jordan inversion, W=8 panels, REDUNDANT per-thread panel
//    inverse in registers. __launch_bounds__(512, 2): VGPR cap 256 so the
//    g[8][8] panel stays in registers (80-VGPR cap spilled it -> 725 us).
// ---------------------------------------------------------------------------
__global__ __launch_bounds__(512, 2) void invert_kernel(
    const float* __restrict__ AAt, float* __restrict__ Sinv)
{
  extern __shared__ float sh[];
  float* M = sh;                       // [128][132]
  float* R = sh + 128 * 132;           // [8][132] pivot-row snapshot
  const int b = blockIdx.x;
  const int tid = threadIdx.x;
  const float* __restrict__ Sb = AAt + (size_t)b * NK * NK;
  for (int idx = tid; idx < NK * NK; idx += 512) {
    M[(idx >> 7) * 132 + (idx & 127)] = Sb[idx];
  }
  __syncthreads();
  const int r = tid & 127;
  const int h = tid >> 7;
  const int c0 = h * 32;

  for (int p = 0; p < 16; p++) {
    const int J0 = p * 8;
    const bool inJ = (r >= J0) && (r < J0 + 8);

    // ---- phase A (reads M only): redundant G8 = inv(M[J,J]) in registers ---
    float g[8][8];
#pragma unroll
    for (int i = 0; i < 8; i++)
#pragma unroll
      for (int j = 0; j < 8; j++) g[i][j] = M[(J0 + i) * 132 + J0 + j];

#pragma unroll
    for (int j = 0; j < 8; j++) {
      const float invd = 1.f / g[j][j];
#pragma unroll
      for (int i = 0; i < 8; i++) {
        if (i == j) continue;
        const float f = g[i][j] * invd;
#pragma unroll
        for (int c = 0; c < 8; c++) {
          if (c == j) continue;
          g[i][c] = fmaf(-f, g[j][c], g[i][c]);
        }
        g[i][j] = -f;
      }
#pragma unroll
      for (int c = 0; c < 8; c++) {
        if (c == j) continue;
        g[j][c] *= invd;
      }
      g[j][j] = invd;
    }

    // coupling factors for my row
    float c8[8];
    if (inJ) {
      const int i0 = r - J0;
#pragma unroll
      for (int q = 0; q < 8; q++) c8[q] = ((i0 == q) ? 1.f : 0.f) - g[i0][q];
    } else {
      float mr8[8];
#pragma unroll
      for (int k = 0; k < 8; k++) mr8[k] = M[r * 132 + J0 + k];
#pragma unroll
      for (int q = 0; q < 8; q++) {
        float a = 0.f;
#pragma unroll
        for (int k = 0; k < 8; k++) a = fmaf(mr8[k], g[k][q], a);
        c8[q] = a;
      }
    }

    // R snapshot of pivot rows (reads M, writes R)
    if (inJ) {
      const int k = r - J0;
#pragma unroll
      for (int i = 0; i < 8; i++)
        *(float4*)&R[k * 132 + c0 + i * 4] = *(const float4*)&M[r * 132 + c0 + i * 4];
    }
    __syncthreads();

    // ---- phase C (writes M): Schur update on my exclusive slab ----
    float4 m[8];
#pragma unroll
    for (int i = 0; i < 8; i++) m[i] = *(const float4*)&M[r * 132 + c0 + i * 4];
#pragma unroll
    for (int k = 0; k < 8; k++) {
      const float f = c8[k];
#pragma unroll
      for (int i = 0; i < 8; i++) {
        float4 rv = *(const float4*)&R[k * 132 + c0 + i * 4];
        m[i].x = fmaf(-f, rv.x, m[i].x);
        m[i].y = fmaf(-f, rv.y, m[i].y);
        m[i].z = fmaf(-f, rv.z, m[i].z);
        m[i].w = fmaf(-f, rv.w, m[i].w);
      }
    }
    // panel columns (2 float4s inside slab hp) get the closed form
    if (h == (J0 >> 5)) {
      const int q4 = (J0 & 31) >> 2;     // first float4 index in slab
      float sp[8];
#pragma unroll
      for (int q = 0; q < 8; q++)
        sp[q] = -c8[q] + (((r - J0) == q) ? 1.f : 0.f);
      m[q4]     = make_float4(sp[0], sp[1], sp[2], sp[3]);
      m[q4 + 1] = make_float4(sp[4], sp[5], sp[6], sp[7]);
    }
#pragma unroll
    for (int i = 0; i < 8; i++) *(float4*)&M[r * 132 + c0 + i * 4] = m[i];
    __syncthreads();
  }

  float* __restrict__ Ob = Sinv + (size_t)b * NK * NK;
  for (int idx = tid; idx < NK * NK; idx += 512) {
    Ob[idx] = M[(idx >> 7) * 132 + (idx & 127)];
  }
}

// ---------------------------------------------------------------------------
// 4b) Newton-Schulz refinement: X <- X(2I - S*X).
// ---------------------------------------------------------------------------
__global__ __launch_bounds__(256) void ns_kernel(
    const float* __restrict__ AAt, float* __restrict__ Sinv)
{
  extern __shared__ float sh[];
  float* S_ = sh;               // [128][132], later holds W = 2I - S*X
  float* X_ = sh + 128 * 132;   // [128][132]
  const int b = blockIdx.x;
  const int tid = threadIdx.x;
  const float* __restrict__ Sg = AAt  + (size_t)b * NK * NK;
  float* __restrict__ Xg       = Sinv + (size_t)b * NK * NK;
  for (int idx = tid; idx < NK * NK; idx += 256) {
    int rr = idx >> 7, cc = idx & 127;
    S_[rr * 132 + cc] = Sg[idx];
    X_[rr * 132 + cc] = Xg[idx];
  }
  __syncthreads();
  const int i0 = (tid >> 4) * 8;
  const int j0 = (tid & 15) * 8;
  float w[8][8];
#pragma unroll
  for (int u = 0; u < 8; u++)
#pragma unroll
    for (int v = 0; v < 8; v++) w[u][v] = 0.f;
  for (int c = 0; c < NK; c++) {
    float sv[8], xv[8];
#pragma unroll
    for (int u = 0; u < 8; u++) sv[u] = S_[(i0 + u) * 132 + c];
#pragma unroll
    for (int v = 0; v < 8; v++) xv[v] = X_[c * 132 + j0 + v];
#pragma unroll
    for (int u = 0; u < 8; u++)
#pragma unroll
      for (int v = 0; v < 8; v++) w[u][v] = fmaf(sv[u], xv[v], w[u][v]);
  }
  __syncthreads();
#pragma unroll
  for (int u = 0; u < 8; u++)
#pragma unroll
    for (int v = 0; v < 8; v++) {
      float val = -w[u][v];
      if (i0 + u == j0 + v) val += 2.f;
      S_[(i0 + u) * 132 + j0 + v] = val;     // S_ now holds W
    }
  __syncthreads();
#pragma unroll
  for (int u = 0; u < 8; u++)
#pragma unroll
    for (int v = 0; v < 8; v++) w[u][v] = 0.f;
  for (int c = 0; c < NK; c++) {
    float xv[8], wv[8];
#pragma unroll
    for (int u = 0; u < 8; u++) xv[u] = X_[(i0 + u) * 132 + c];
#pragma unroll
    for (int v = 0; v < 8; v++) wv[v] = S_[c * 132 + j0 + v];
#pragma unroll
    for (int u = 0; u < 8; u++)
#pragma unroll
      for (int v = 0; v < 8; v++) w[u][v] = fmaf(xv[u], wv[v], w[u][v]);
  }
#pragma unroll
  for (int u = 0; u < 8; u++)
#pragma unroll
    for (int v = 0; v < 8; v++)
      Xg[(size_t)(i0 + u) * NK + j0 + v] = w[u][v];
}

// ---------------------------------------------------------------------------
// 5) Solve via Neumann fixed point (2 iterations).
// ---------------------------------------------------------------------------
__global__ __launch_bounds__(256) void solve_kernel(
    const float* __restrict__ Sinv, const float* __restrict__ BAt,
    const float* __restrict__ Dm, float* __restrict__ Cxy)
{
  extern __shared__ float sh[];
  float* SinvS = sh;               // [128][132]
  float* ZS    = sh + 128 * 132;   // [128][133]
  const int b = blockIdx.x;
  const int tid = threadIdx.x;
  const float* __restrict__ Sb = Sinv + (size_t)b * NK * NK;
  const float* __restrict__ Rb = BAt  + (size_t)b * NK * NK;
  const float* __restrict__ Db = Dm   + (size_t)b * NK * NK;
  for (int idx = tid; idx < NK * NK; idx += 256) {
    int r = idx >> 7, c = idx & 127;
    SinvS[r * 132 + c] = Sb[idx];
    ZS[r * 133 + c]    = Rb[idx];
  }
  __syncthreads();
  const int i0 = (tid >> 4) * 8;
  const int r0 = (tid & 15) * 8;
  float Y[8][8], X[8][8];
#pragma unroll
  for (int u = 0; u < 8; u++)
#pragma unroll
    for (int v = 0; v < 8; v++) Y[u][v] = 0.f;

  for (int c = 0; c < NK; c++) {
    float4 s0 = *(const float4*)&SinvS[c * 132 + r0];
    float4 s1 = *(const float4*)&SinvS[c * 132 + r0 + 4];
#pragma unroll
    for (int u = 0; u < 8; u++) {
      float z = ZS[(i0 + u) * 133 + c];
      Y[u][0] = fmaf(z, s0.x, Y[u][0]);
      Y[u][1] = fmaf(z, s0.y, Y[u][1]);
      Y[u][2] = fmaf(z, s0.z, Y[u][2]);
      Y[u][3] = fmaf(z, s0.w, Y[u][3]);
      Y[u][4] = fmaf(z, s1.x, Y[u][4]);
      Y[u][5] = fmaf(z, s1.y, Y[u][5]);
      Y[u][6] = fmaf(z, s1.z, Y[u][6]);
      Y[u][7] = fmaf(z, s1.w, Y[u][7]);
    }
  }
#pragma unroll
  for (int u = 0; u < 8; u++)
#pragma unroll
    for (int v = 0; v < 8; v++) X[u][v] = Y[u][v];

  for (int it = 0; it < 2; it++) {
    __syncthreads();
#pragma unroll
    for (int u = 0; u < 8; u++) {
      const float* drow = Db + (size_t)(i0 + u) * NK + r0;
      float* zrow = ZS + (i0 + u) * 133 + r0;
#pragma unroll
      for (int v = 0; v < 8; v++) zrow[v] = LMBDA * drow[v] * X[u][v];
    }
    __syncthreads();
#pragma unroll
    for (int u = 0; u < 8; u++)
#pragma unroll
      for (int v = 0; v < 8; v++) X[u][v] = Y[u][v];
    for (int c = 0; c < NK; c++) {
      float4 s0 = *(const float4*)&SinvS[c * 132 + r0];
      float4 s1 = *(const float4*)&SinvS[c * 132 + r0 + 4];
#pragma unroll
      for (int u = 0; u < 8; u++) {
        float z = ZS[(i0 + u) * 133 + c];
        X[u][0] = fmaf(-z, s0.x, X[u][0]);
        X[u][1] = fmaf(-z, s0.y, X[u][1]);
        X[u][2] = fmaf(-z, s0.z, X[u][2]);
        X[u][3] = fmaf(-z, s0.w, X[u][3]);
        X[u][4] = fmaf(-z, s1.x, X[u][4]);
        X[u][5] = fmaf(-z, s1.y, X[u][5]);
        X[u][6] = fmaf(-z, s1.z, X[u][6]);
        X[u][7] = fmaf(-z, s1.w, X[u][7]);
      }
    }
  }
  float* __restrict__ Ob = Cxy + ((size_t)b * NK + i0) * NK + r0;
#pragma unroll
  for (int u = 0; u < 8; u++) {
    float4 o0 = make_float4(X[u][0], X[u][1], X[u][2], X[u][3]);
    float4 o1 = make_float4(X[u][4], X[u][5], X[u][6], X[u][7]);
    *(float4*)(Ob + (size_t)u * NK)     = o0;
    *(float4*)(Ob + (size_t)u * NK + 4) = o1;
  }
}

} // anonymous namespace

extern "C" void kernel_launch(void* const* d_in, const int* in_sizes, int n_in,
                              void* d_out, int out_size, void* d_ws, size_t ws_size,
                              hipStream_t stream) {
  (void)in_sizes; (void)n_in; (void)out_size;
  const float* feat_x  = (const float*)d_in[0];
  const float* feat_y  = (const float*)d_in[1];
  const float* evals_x = (const float*)d_in[2];
  const float* evals_y = (const float*)d_in[3];
  const float* etx     = (const float*)d_in[4];
  const float* ety     = (const float*)d_in[5];
  float* out = (float*)d_out;
  float* ws  = (float*)d_ws;

  float* A    = ws;
  float* Bm   = ws + 262144;
  float* AAt  = ws + 524288;
  float* BAt  = ws + 655360;
  float* Dm   = ws + 786432;
  float* Sinv = ws + 917504;
  float* P    = ws + 1048576;

  const bool use_partial = ws_size >= (size_t)(1048576 + 8388608) * 4;

  constexpr int INV_LDS = (128 * 132 + 8 * 132) * 4;        // 71808 B
  constexpr int NS_LDS  = (2 * 128 * 132) * 4;              // 135168 B
  hipFuncSetAttribute((const void*)invert_kernel,
                      hipFuncAttributeMaxDynamicSharedMemorySize, INV_LDS);
  hipFuncSetAttribute((const void*)ns_kernel,
                      hipFuncAttributeMaxDynamicSharedMemorySize, NS_LDS);
  hipFuncSetAttribute((const void*)solve_kernel,
                      hipFuncAttributeMaxDynamicSharedMemorySize, (128 * 132 + 128 * 133) * 4);

  if (use_partial) {
    proj_mfma<0><<<dim3(CHUNKS, 2, 16), 512, 0, stream>>>(etx, feat_x, ety, feat_y, A, Bm, P);
    reduce_kernel<<<dim3(512), 256, 0, stream>>>(P, ws);
  } else {
    hipMemsetAsync(A, 0, (size_t)524288 * sizeof(float), stream);
    proj_mfma<1><<<dim3(CHUNKS, 2, 16), 512, 0, stream>>>(etx, feat_x, ety, feat_y, A, Bm, P);
  }
  gram_kernel<<<dim3(16, 8), 256, 0, stream>>>(A, Bm, AAt, BAt);
  mask_kernel<<<dim3(8), 256, 0, stream>>>(evals_x, evals_y, Dm);
  invert_kernel<<<dim3(8), 512, INV_LDS, stream>>>(AAt, Sinv);
  ns_kernel<<<dim3(8), 256, NS_LDS, stream>>>(AAt, Sinv);
  ns_kernel<<<dim3(8), 256, NS_LDS, stream>>>(AAt, Sinv);
  solve_kernel<<<dim3(8), 256, (128 * 132 + 128 * 133) * 4, stream>>>(Sinv, BAt, Dm, out);
}

// Round 8
// 361.896 us; speedup vs baseline: 2.7781x; 2.7737x over previous
//
#include <hip/hip_runtime.h>
#include <hip/hip_bf16.h>

namespace {

constexpr int NB = 8;
constexpr int NV = 20000;
constexpr int NC = 256;
constexpr int NK = 128;
constexpr float LMBDA = 100.0f;
constexpr int KSTEP = 32;
constexpr int CHUNKS = 16;      // v-chunks; chunk 0 gets 40 steps, rest 39

typedef __attribute__((ext_vector_type(8))) short bf16x8;
typedef __attribute__((ext_vector_type(4))) float f32x4;

__device__ __forceinline__ ushort f2bf(float x) {
  uint u = __float_as_uint(x);
  u += 0x7fffu + ((u >> 16) & 1u);
  return (ushort)(u >> 16);
}
__device__ __forceinline__ float bf2f(ushort h) { return __uint_as_float(((uint)h) << 16); }

// ---------------------------------------------------------------------------
// 1) Spectral projection via split-bf16 MFMA (hi*hi + hi*lo + lo*hi).
// ---------------------------------------------------------------------------
template <int MODE>
__global__ __launch_bounds__(512, 4) void proj_mfma(
    const float* __restrict__ Ex, const float* __restrict__ Fx,
    const float* __restrict__ Ey, const float* __restrict__ Fy,
    float* __restrict__ A, float* __restrict__ Bm, float* __restrict__ P)
{
  const int chunk = blockIdx.x;            // 0..15
  const int ct    = blockIdx.y;            // 0..1 (c half)
  const int bs    = blockIdx.z;            // b*2+side
  const int b     = bs >> 1;
  const int side  = bs & 1;
  const float* __restrict__ E = (side ? Ey : Ex) + (size_t)b * NK * NV;
  const float* __restrict__ F = (side ? Fy : Fx) + (size_t)b * NV * NC;
  float* __restrict__ Out = (side ? Bm : A) + (size_t)b * NK * NC;
  const int cb = ct * 128;

  const int start = chunk * 39 + (chunk > 0 ? 1 : 0);
  const int nsteps = 39 + (chunk == 0 ? 1 : 0);
  const int v0 = start * KSTEP;

  __shared__ __align__(16) ushort AH[2][8][64][8];
  __shared__ __align__(16) ushort BH[2][8][64][8];

  const int tid  = threadIdx.x;
  const int lane = tid & 63;
  const int w    = tid >> 6;
  const int wm   = w >> 2;       // 0..1 (64-row group)
  const int wn   = w & 3;        // 0..3 (32-col group)
  const int lrow = lane >> 4;    // 0..3
  const int lcol = lane & 15;

  const int ek  = tid >> 2;
  const int evg = tid & 3;
  const int ef  = ek >> 4;
  const int entE = (((ek & 15) + evg * 4) & 15) + evg * 16;
  const float* Eptr = E + (size_t)ek * NV + v0 + evg * 8;

  const int fp  = tid & 15;
  const int fc0 = (tid >> 4) * 4;
  const int fcg = fc0 >> 4;
  const int fclow = fc0 & 15;
  const int fvg = fp >> 2;
  const int fsp = fp & 3;
  const float* Fptr = F + (size_t)(v0 + 2 * fp) * NC + cb + fc0;

  f32x4 acc[4][2];
#pragma unroll
  for (int fi = 0; fi < 4; fi++)
#pragma unroll
    for (int ni = 0; ni < 2; ni++) acc[fi][ni] = (f32x4)0.f;

  const int entA = (((lcol) + lrow * 4) & 15) + lrow * 16;

  float4 e0 = *(const float4*)(Eptr);
  float4 e1 = *(const float4*)(Eptr + 4);
  float4 f0 = *(const float4*)(Fptr);
  float4 f1 = *(const float4*)(Fptr + NC);

  for (int s = 0; s < nsteps; s++) {
    {
      const float v[8] = {e0.x, e0.y, e0.z, e0.w, e1.x, e1.y, e1.z, e1.w};
      uint hiw[4], low[4];
#pragma unroll
      for (int i = 0; i < 4; i++) {
        float a = v[2 * i], c = v[2 * i + 1];
        ushort ha = f2bf(a), hc = f2bf(c);
        hiw[i] = (uint)ha | ((uint)hc << 16);
        low[i] = (uint)f2bf(a - bf2f(ha)) | ((uint)f2bf(c - bf2f(hc)) << 16);
      }
      *(uint4*)&AH[0][ef][entE][0] = make_uint4(hiw[0], hiw[1], hiw[2], hiw[3]);
      *(uint4*)&AH[1][ef][entE][0] = make_uint4(low[0], low[1], low[2], low[3]);

      const float* fa = (const float*)&f0;
      const float* fb = (const float*)&f1;
#pragma unroll
      for (int j = 0; j < 4; j++) {
        int ent = ((fclow + j + fcg) & 15) + fvg * 16;
        float a = fa[j], c = fb[j];
        ushort ha = f2bf(a), hc = f2bf(c);
        *(uint*)&BH[0][fcg][ent][2 * fsp] = (uint)ha | ((uint)hc << 16);
        *(uint*)&BH[1][fcg][ent][2 * fsp] =
            (uint)f2bf(a - bf2f(ha)) | ((uint)f2bf(c - bf2f(hc)) << 16);
      }
    }
    __syncthreads();

    if (s + 1 < nsteps) {
      Eptr += KSTEP;
      Fptr += (size_t)KSTEP * NC;
      e0 = *(const float4*)(Eptr);
      e1 = *(const float4*)(Eptr + 4);
      f0 = *(const float4*)(Fptr);
      f1 = *(const float4*)(Fptr + NC);
    }

    {
      bf16x8 bHf[2], bLf[2];
#pragma unroll
      for (int ni = 0; ni < 2; ni++) {
        int cg = wn * 2 + ni;
        int entB = ((lcol + cg) & 15) + lrow * 16;
        bHf[ni] = *(const bf16x8*)&BH[0][cg][entB][0];
        bLf[ni] = *(const bf16x8*)&BH[1][cg][entB][0];
      }
#pragma unroll
      for (int fi = 0; fi < 4; fi++) {
        bf16x8 aH = *(const bf16x8*)&AH[0][wm * 4 + fi][entA][0];
        bf16x8 aL = *(const bf16x8*)&AH[1][wm * 4 + fi][entA][0];
#pragma unroll
        for (int ni = 0; ni < 2; ni++) {
          acc[fi][ni] = __builtin_amdgcn_mfma_f32_16x16x32_bf16(aH, bHf[ni], acc[fi][ni], 0, 0, 0);
          acc[fi][ni] = __builtin_amdgcn_mfma_f32_16x16x32_bf16(aH, bLf[ni], acc[fi][ni], 0, 0, 0);
          acc[fi][ni] = __builtin_amdgcn_mfma_f32_16x16x32_bf16(aL, bHf[ni], acc[fi][ni], 0, 0, 0);
        }
      }
    }
    __syncthreads();
  }

#pragma unroll
  for (int fi = 0; fi < 4; fi++) {
#pragma unroll
    for (int ni = 0; ni < 2; ni++) {
      const float* av = (const float*)&acc[fi][ni];
#pragma unroll
      for (int q = 0; q < 4; q++) {
        int row = wm * 64 + fi * 16 + lrow * 4 + q;
        int col = cb + wn * 32 + ni * 16 + lcol;
        if (MODE == 0) {
          P[(((size_t)chunk * 16 + bs) * NK + row) * NC + col] = av[q];
        } else {
          atomicAdd(&Out[(size_t)row * NC + col], av[q]);
        }
      }
    }
  }
}

__global__ __launch_bounds__(256) void reduce_kernel(
    const float* __restrict__ P, float* __restrict__ AB)
{
  const int g = blockIdx.x * 256 + threadIdx.x;
  const int bsi = g >> 13;
  const int rem4 = g & 8191;
  const int side = bsi & 1, b = bsi >> 1;
  float4 s = make_float4(0.f, 0.f, 0.f, 0.f);
#pragma unroll
  for (int ch = 0; ch < CHUNKS; ch++) {
    float4 v = *(const float4*)(P + (((size_t)ch * 16 + bsi) * 8192 + rem4) * 4);
    s.x += v.x; s.y += v.y; s.z += v.z; s.w += v.w;
  }
  *(float4*)(AB + ((size_t)side * 262144 + (size_t)b * 8192 * 4 + (size_t)rem4 * 4)) = s;
}

// ---------------------------------------------------------------------------
// 2) Gram
// ---------------------------------------------------------------------------
__global__ __launch_bounds__(256) void gram_kernel(
    const float* __restrict__ A, const float* __restrict__ Bm,
    float* __restrict__ AAt, float* __restrict__ BAt)
{
  const int i0 = blockIdx.x * 8;
  const int b  = blockIdx.y;
  __shared__ float Xi[16][260];
  const float* __restrict__ Ab = A  + (size_t)b * NK * NC;
  const float* __restrict__ Bb = Bm + (size_t)b * NK * NC;
  const int tid = threadIdx.x;
  for (int idx = tid; idx < 16 * 64; idx += 256) {
    int row = idx >> 6, c4 = idx & 63;
    const float* src = (row < 8) ? (Ab + (size_t)(i0 + row) * NC)
                                 : (Bb + (size_t)(i0 + row - 8) * NC);
    *(float4*)&Xi[row][c4 * 4] = *(const float4*)(src + c4 * 4);
  }
  __syncthreads();
  const int j = tid & 127;
  const int m = tid >> 7;
  const float* __restrict__ Arow = Ab + (size_t)j * NC;
  float accv[8];
#pragma unroll
  for (int i = 0; i < 8; i++) accv[i] = 0.f;
  for (int c4 = 0; c4 < 64; c4++) {
    float4 a4 = *(const float4*)(Arow + c4 * 4);
#pragma unroll
    for (int i = 0; i < 8; i++) {
      float4 x4 = *(const float4*)&Xi[m * 8 + i][c4 * 4];
      accv[i] = fmaf(x4.x, a4.x, accv[i]);
      accv[i] = fmaf(x4.y, a4.y, accv[i]);
      accv[i] = fmaf(x4.z, a4.z, accv[i]);
      accv[i] = fmaf(x4.w, a4.w, accv[i]);
    }
  }
  float* Outp = (m ? BAt : AAt) + ((size_t)b * NK + i0) * NK + j;
#pragma unroll
  for (int i = 0; i < 8; i++) Outp[(size_t)i * NK] = accv[i];
}

// ---------------------------------------------------------------------------
// 3) Mask D
// ---------------------------------------------------------------------------
__global__ __launch_bounds__(256) void mask_kernel(
    const float* __restrict__ evx, const float* __restrict__ evy,
    float* __restrict__ Dm)
{
  const int b = blockIdx.x;
  const int tid = threadIdx.x;
  __shared__ float red[256];
  __shared__ float t1x[128], t2x[128], t1y[128], t2y[128];
  float v = (tid < 128) ? evx[b * 128 + tid] : evy[b * 128 + (tid - 128)];
  red[tid] = v;
  __syncthreads();
  for (int sft = 128; sft > 0; sft >>= 1) {
    if (tid < sft) red[tid] = fmaxf(red[tid], red[tid + sft]);
    __syncthreads();
  }
  const float inv_scale = 1.0f / red[0];
  if (tid < 128) {
    float e = evx[b * 128 + tid] * inv_scale;
    float g = sqrtf(e);
    float d = 1.f / (g * g + 1.f);
    t1x[tid] = g * d;  t2x[tid] = d;
  } else {
    int i = tid - 128;
    float e = evy[b * 128 + i] * inv_scale;
    float g = sqrtf(e);
    float d = 1.f / (g * g + 1.f);
    t1y[i] = g * d;  t2y[i] = d;
  }
  __syncthreads();
  float* __restrict__ Db = Dm + (size_t)b * NK * NK;
  for (int idx = tid; idx < NK * NK; idx += 256) {
    int i = idx >> 7, jj = idx & 127;
    float re = t1y[i] - t1x[jj];
    float im = t2y[i] - t2x[jj];
    Db[idx] = re * re + im * im;
  }
}

// ---------------------------------------------------------------------------
// 4) Blocked Gauss-Jordan inversion, W=8 panels, redundant per-thread panel
//    inverse. ALL register-array indices are compile-time constants (rule #20:
//    runtime-indexed reg arrays demote to scratch -> that was the 726 us).
// ---------------------------------------------------------------------------
__global__ __launch_bounds__(512) void invert_kernel(
    const float* __restrict__ AAt, float* __restrict__ Sinv)
{
  extern __shared__ float sh[];
  float* M = sh;                       // [128][132]
  float* R = sh + 128 * 132;           // [8][132] pivot-row snapshot
  const int b = blockIdx.x;
  const int tid = threadIdx.x;
  const float* __restrict__ Sb = AAt + (size_t)b * NK * NK;
  for (int idx = tid; idx < NK * NK; idx += 512) {
    M[(idx >> 7) * 132 + (idx & 127)] = Sb[idx];
  }
  __syncthreads();
  const int r = tid & 127;
  const int h = tid >> 7;
  const int c0 = h * 32;

  for (int p = 0; p < 16; p++) {
    const int J0 = p * 8;
    const bool inJ = (r >= J0) && (r < J0 + 8);
    const int i0 = r - J0;             // row-in-panel (valid only when inJ)

    // ---- phase A (reads M only): redundant G8 = inv(M[J,J]) in registers ---
    float g[8][8];
#pragma unroll
    for (int i = 0; i < 8; i++)
#pragma unroll
      for (int j = 0; j < 8; j++) g[i][j] = M[(J0 + i) * 132 + J0 + j];

#pragma unroll
    for (int j = 0; j < 8; j++) {
      const float invd = 1.f / g[j][j];
#pragma unroll
      for (int i = 0; i < 8; i++) {
        if (i == j) continue;
        const float f = g[i][j] * invd;
#pragma unroll
        for (int c = 0; c < 8; c++) {
          if (c == j) continue;
          g[i][c] = fmaf(-f, g[j][c], g[i][c]);
        }
        g[i][j] = -f;
      }
#pragma unroll
      for (int c = 0; c < 8; c++) {
        if (c == j) continue;
        g[j][c] *= invd;
      }
      g[j][j] = invd;
    }

    // coupling factors for my row — static indices only
    float c8[8];
    if (inJ) {
#pragma unroll
      for (int q = 0; q < 8; q++) {
        float v = 0.f;
#pragma unroll
        for (int i = 0; i < 8; i++)
          if (i0 == i) v = g[i][q];            // static index, runtime select
        c8[q] = ((i0 == q) ? 1.f : 0.f) - v;
      }
    } else {
      float mr8[8];
#pragma unroll
      for (int k = 0; k < 8; k++) mr8[k] = M[r * 132 + J0 + k];
#pragma unroll
      for (int q = 0; q < 8; q++) {
        float a = 0.f;
#pragma unroll
        for (int k = 0; k < 8; k++) a = fmaf(mr8[k], g[k][q], a);
        c8[q] = a;
      }
    }

    // R snapshot of pivot rows (reads M, writes R)
    if (inJ) {
#pragma unroll
      for (int i = 0; i < 8; i++)
        *(float4*)&R[i0 * 132 + c0 + i * 4] = *(const float4*)&M[r * 132 + c0 + i * 4];
    }
    __syncthreads();

    // ---- phase C (writes M): Schur update on my exclusive slab ----
    float4 m[8];
#pragma unroll
    for (int i = 0; i < 8; i++) m[i] = *(const float4*)&M[r * 132 + c0 + i * 4];
#pragma unroll
    for (int k = 0; k < 8; k++) {
      const float f = c8[k];
#pragma unroll
      for (int i = 0; i < 8; i++) {
        float4 rv = *(const float4*)&R[k * 132 + c0 + i * 4];
        m[i].x = fmaf(-f, rv.x, m[i].x);
        m[i].y = fmaf(-f, rv.y, m[i].y);
        m[i].z = fmaf(-f, rv.z, m[i].z);
        m[i].w = fmaf(-f, rv.w, m[i].w);
      }
    }
    // panel columns get the closed form: -c8 (+I on pivot rows).
    // Static indices with runtime predicates (q4 depends on p -> runtime).
    {
      const bool panelH = (h == (J0 >> 5));
      const int q4 = (J0 & 31) >> 2;           // first float4 slot in slab
      float sp[8];
#pragma unroll
      for (int q = 0; q < 8; q++)
        sp[q] = -c8[q] + ((inJ && i0 == q) ? 1.f : 0.f);
      const float4 lo = make_float4(sp[0], sp[1], sp[2], sp[3]);
      const float4 hi = make_float4(sp[4], sp[5], sp[6], sp[7]);
#pragma unroll
      for (int i = 0; i < 8; i++) {
        if (panelH && i == q4)     m[i] = lo;
        if (panelH && i == q4 + 1) m[i] = hi;
      }
    }
#pragma unroll
    for (int i = 0; i < 8; i++) *(float4*)&M[r * 132 + c0 + i * 4] = m[i];
    __syncthreads();
  }

  float* __restrict__ Ob = Sinv + (size_t)b * NK * NK;
  for (int idx = tid; idx < NK * NK; idx += 512) {
    Ob[idx] = M[(idx >> 7) * 132 + (idx & 127)];
  }
}

// ---------------------------------------------------------------------------
// 4b) Newton-Schulz refinement: X <- X(2I - S*X).
// ---------------------------------------------------------------------------
__global__ __launch_bounds__(256) void ns_kernel(
    const float* __restrict__ AAt, float* __restrict__ Sinv)
{
  extern __shared__ float sh[];
  float* S_ = sh;               // [128][132], later holds W = 2I - S*X
  float* X_ = sh + 128 * 132;   // [128][132]
  const int b = blockIdx.x;
  const int tid = threadIdx.x;
  const float* __restrict__ Sg = AAt  + (size_t)b * NK * NK;
  float* __restrict__ Xg       = Sinv + (size_t)b * NK * NK;
  for (int idx = tid; idx < NK * NK; idx += 256) {
    int rr = idx >> 7, cc = idx & 127;
    S_[rr * 132 + cc] = Sg[idx];
    X_[rr * 132 + cc] = Xg[idx];
  }
  __syncthreads();
  const int i0 = (tid >> 4) * 8;
  const int j0 = (tid & 15) * 8;
  float w[8][8];
#pragma unroll
  for (int u = 0; u < 8; u++)
#pragma unroll
    for (int v = 0; v < 8; v++) w[u][v] = 0.f;
  for (int c = 0; c < NK; c++) {
    float sv[8], xv[8];
#pragma unroll
    for (int u = 0; u < 8; u++) sv[u] = S_[(i0 + u) * 132 + c];
#pragma unroll
    for (int v = 0; v < 8; v++) xv[v] = X_[c * 132 + j0 + v];
#pragma unroll
    for (int u = 0; u < 8; u++)
#pragma unroll
      for (int v = 0; v < 8; v++) w[u][v] = fmaf(sv[u], xv[v], w[u][v]);
  }
  __syncthreads();
#pragma unroll
  for (int u = 0; u < 8; u++)
#pragma unroll
    for (int v = 0; v < 8; v++) {
      float val = -w[u][v];
      if (i0 + u == j0 + v) val += 2.f;
      S_[(i0 + u) * 132 + j0 + v] = val;     // S_ now holds W
    }
  __syncthreads();
#pragma unroll
  for (int u = 0; u < 8; u++)
#pragma unroll
    for (int v = 0; v < 8; v++) w[u][v] = 0.f;
  for (int c = 0; c < NK; c++) {
    float xv[8], wv[8];
#pragma unroll
    for (int u = 0; u < 8; u++) xv[u] = X_[(i0 + u) * 132 + c];
#pragma unroll
    for (int v = 0; v < 8; v++) wv[v] = S_[c * 132 + j0 + v];
#pragma unroll
    for (int u = 0; u < 8; u++)
#pragma unroll
      for (int v = 0; v < 8; v++) w[u][v] = fmaf(xv[u], wv[v], w[u][v]);
  }
#pragma unroll
  for (int u = 0; u < 8; u++)
#pragma unroll
    for (int v = 0; v < 8; v++)
      Xg[(size_t)(i0 + u) * NK + j0 + v] = w[u][v];
}

// ---------------------------------------------------------------------------
// 5) Solve via Neumann fixed point (2 iterations).
// ---------------------------------------------------------------------------
__global__ __launch_bounds__(256) void solve_kernel(
    const float* __restrict__ Sinv, const float* __restrict__ BAt,
    const float* __restrict__ Dm, float* __restrict__ Cxy)
{
  extern __shared__ float sh[];
  float* SinvS = sh;               // [128][132]
  float* ZS    = sh + 128 * 132;   // [128][133]
  const int b = blockIdx.x;
  const int tid = threadIdx.x;
  const float* __restrict__ Sb = Sinv + (size_t)b * NK * NK;
  const float* __restrict__ Rb = BAt  + (size_t)b * NK * NK;
  const float* __restrict__ Db = Dm   + (size_t)b * NK * NK;
  for (int idx = tid; idx < NK * NK; idx += 256) {
    int r = idx >> 7, c = idx & 127;
    SinvS[r * 132 + c] = Sb[idx];
    ZS[r * 133 + c]    = Rb[idx];
  }
  __syncthreads();
  const int i0 = (tid >> 4) * 8;
  const int r0 = (tid & 15) * 8;
  float Y[8][8], X[8][8];
#pragma unroll
  for (int u = 0; u < 8; u++)
#pragma unroll
    for (int v = 0; v < 8; v++) Y[u][v] = 0.f;

  for (int c = 0; c < NK; c++) {
    float4 s0 = *(const float4*)&SinvS[c * 132 + r0];
    float4 s1 = *(const float4*)&SinvS[c * 132 + r0 + 4];
#pragma unroll
    for (int u = 0; u < 8; u++) {
      float z = ZS[(i0 + u) * 133 + c];
      Y[u][0] = fmaf(z, s0.x, Y[u][0]);
      Y[u][1] = fmaf(z, s0.y, Y[u][1]);
      Y[u][2] = fmaf(z, s0.z, Y[u][2]);
      Y[u][3] = fmaf(z, s0.w, Y[u][3]);
      Y[u][4] = fmaf(z, s1.x, Y[u][4]);
      Y[u][5] = fmaf(z, s1.y, Y[u][5]);
      Y[u][6] = fmaf(z, s1.z, Y[u][6]);
      Y[u][7] = fmaf(z, s1.w, Y[u][7]);
    }
  }
#pragma unroll
  for (int u = 0; u < 8; u++)
#pragma unroll
    for (int v = 0; v < 8; v++) X[u][v] = Y[u][v];

  for (int it = 0; it < 2; it++) {
    __syncthreads();
#pragma unroll
    for (int u = 0; u < 8; u++) {
      const float* drow = Db + (size_t)(i0 + u) * NK + r0;
      float* zrow = ZS + (i0 + u) * 133 + r0;
#pragma unroll
      for (int v = 0; v < 8; v++) zrow[v] = LMBDA * drow[v] * X[u][v];
    }
    __syncthreads();
#pragma unroll
    for (int u = 0; u < 8; u++)
#pragma unroll
      for (int v = 0; v < 8; v++) X[u][v] = Y[u][v];
    for (int c = 0; c < NK; c++) {
      float4 s0 = *(const float4*)&SinvS[c * 132 + r0];
      float4 s1 = *(const float4*)&SinvS[c * 132 + r0 + 4];
#pragma unroll
      for (int u = 0; u < 8; u++) {
        float z = ZS[(i0 + u) * 133 + c];
        X[u][0] = fmaf(-z, s0.x, X[u][0]);
        X[u][1] = fmaf(-z, s0.y, X[u][1]);
        X[u][2] = fmaf(-z, s0.z, X[u][2]);
        X[u][3] = fmaf(-z, s0.w, X[u][3]);
        X[u][4] = fmaf(-z, s1.x, X[u][4]);
        X[u][5] = fmaf(-z, s1.y, X[u][5]);
        X[u][6] = fmaf(-z, s1.z, X[u][6]);
        X[u][7] = fmaf(-z, s1.w, X[u][7]);
      }
    }
  }
  float* __restrict__ Ob = Cxy + ((size_t)b * NK + i0) * NK + r0;
#pragma unroll
  for (int u = 0; u < 8; u++) {
    float4 o0 = make_float4(X[u][0], X[u][1], X[u][2], X[u][3]);
    float4 o1 = make_float4(X[u][4], X[u][5], X[u][6], X[u][7]);
    *(float4*)(Ob + (size_t)u * NK)     = o0;
    *(float4*)(Ob + (size_t)u * NK + 4) = o1;
  }
}

} // anonymous namespace

extern "C" void kernel_launch(void* const* d_in, const int* in_sizes, int n_in,
                              void* d_out, int out_size, void* d_ws, size_t ws_size,
                              hipStream_t stream) {
  (void)in_sizes; (void)n_in; (void)out_size;
  const float* feat_x  = (const float*)d_in[0];
  const float* feat_y  = (const float*)d_in[1];
  const float* evals_x = (const float*)d_in[2];
  const float* evals_y = (const float*)d_in[3];
  const float* etx     = (const float*)d_in[4];
  const float* ety     = (const float*)d_in[5];
  float* out = (float*)d_out;
  float* ws  = (float*)d_ws;

  float* A    = ws;
  float* Bm   = ws + 262144;
  float* AAt  = ws + 524288;
  float* BAt  = ws + 655360;
  float* Dm   = ws + 786432;
  float* Sinv = ws + 917504;
  float* P    = ws + 1048576;

  const bool use_partial = ws_size >= (size_t)(1048576 + 8388608) * 4;

  constexpr int INV_LDS = (128 * 132 + 8 * 132) * 4;        // 71808 B
  constexpr int NS_LDS  = (2 * 128 * 132) * 4;              // 135168 B
  hipFuncSetAttribute((const void*)invert_kernel,
                      hipFuncAttributeMaxDynamicSharedMemorySize, INV_LDS);
  hipFuncSetAttribute((const void*)ns_kernel,
                      hipFuncAttributeMaxDynamicSharedMemorySize, NS_LDS);
  hipFuncSetAttribute((const void*)solve_kernel,
                      hipFuncAttributeMaxDynamicSharedMemorySize, (128 * 132 + 128 * 133) * 4);

  if (use_partial) {
    proj_mfma<0><<<dim3(CHUNKS, 2, 16), 512, 0, stream>>>(etx, feat_x, ety, feat_y, A, Bm, P);
    reduce_kernel<<<dim3(512), 256, 0, stream>>>(P, ws);
  } else {
    hipMemsetAsync(A, 0, (size_t)524288 * sizeof(float), stream);
    proj_mfma<1><<<dim3(CHUNKS, 2, 16), 512, 0, stream>>>(etx, feat_x, ety, feat_y, A, Bm, P);
  }
  gram_kernel<<<dim3(16, 8), 256, 0, stream>>>(A, Bm, AAt, BAt);
  mask_kernel<<<dim3(8), 256, 0, stream>>>(evals_x, evals_y, Dm);
  invert_kernel<<<dim3(8), 512, INV_LDS, stream>>>(AAt, Sinv);
  ns_kernel<<<dim3(8), 256, NS_LDS, stream>>>(AAt, Sinv);
  ns_kernel<<<dim3(8), 256, NS_LDS, stream>>>(AAt, Sinv);
  solve_kernel<<<dim3(8), 256, (128 * 132 + 128 * 133) * 4, stream>>>(Sinv, BAt, Dm, out);
}

// Round 10
// 355.815 us; speedup vs baseline: 2.8256x; 1.0171x over previous
//
#include <hip/hip_runtime.h>
#include <hip/hip_bf16.h>

namespace {

constexpr int NB = 8;
constexpr int NV = 20000;
constexpr int NC = 256;
constexpr int NK = 128;
constexpr float LMBDA = 100.0f;
constexpr int KSTEP = 32;
constexpr int CHUNKS = 16;      // v-chunks; chunk 0 gets 40 steps, rest 39

typedef __attribute__((ext_vector_type(8))) short bf16x8;
typedef __attribute__((ext_vector_type(4))) float f32x4;

__device__ __forceinline__ ushort f2bf(float x) {
  uint u = __float_as_uint(x);
  u += 0x7fffu + ((u >> 16) & 1u);
  return (ushort)(u >> 16);
}
__device__ __forceinline__ float bf2f(ushort h) { return __uint_as_float(((uint)h) << 16); }

// ---------------------------------------------------------------------------
// 1) Spectral projection via split-bf16 MFMA (hi*hi + hi*lo + lo*hi).
//    Double-buffered LDS (2 x 32 KB), ONE barrier per K-step.
// ---------------------------------------------------------------------------
template <int MODE>
__global__ __launch_bounds__(512, 4) void proj_mfma(
    const float* __restrict__ Ex, const float* __restrict__ Fx,
    const float* __restrict__ Ey, const float* __restrict__ Fy,
    float* __restrict__ A, float* __restrict__ Bm, float* __restrict__ P)
{
  extern __shared__ ushort smem[];         // 2 bufs x (AH 8192 + BH 8192) ushorts

  const int chunk = blockIdx.x;            // 0..15
  const int ct    = blockIdx.y;            // 0..1 (c half)
  const int bs    = blockIdx.z;            // b*2+side
  const int b     = bs >> 1;
  const int side  = bs & 1;
  const float* __restrict__ E = (side ? Ey : Ex) + (size_t)b * NK * NV;
  const float* __restrict__ F = (side ? Fy : Fx) + (size_t)b * NV * NC;
  float* __restrict__ Out = (side ? Bm : A) + (size_t)b * NK * NC;
  const int cb = ct * 128;

  const int start = chunk * 39 + (chunk > 0 ? 1 : 0);
  const int nsteps = 39 + (chunk == 0 ? 1 : 0);
  const int v0 = start * KSTEP;

  const int tid  = threadIdx.x;
  const int lane = tid & 63;
  const int w    = tid >> 6;
  const int wm   = w >> 2;       // 0..1 (64-row group)
  const int wn   = w & 3;        // 0..3 (32-col group)
  const int lrow = lane >> 4;    // 0..3
  const int lcol = lane & 15;

  const int ek  = tid >> 2;
  const int evg = tid & 3;
  const int ef  = ek >> 4;
  const int entE = (((ek & 15) + evg * 4) & 15) + evg * 16;
  const float* Erow = E + (size_t)ek * NV + v0 + evg * 8;

  const int fp  = tid & 15;
  const int fc0 = (tid >> 4) * 4;
  const int fcg = fc0 >> 4;
  const int fclow = fc0 & 15;
  const int fvg = fp >> 2;
  const int fsp = fp & 3;

  f32x4 acc[4][2];
#pragma unroll
  for (int fi = 0; fi < 4; fi++)
#pragma unroll
    for (int ni = 0; ni < 2; ni++) acc[fi][ni] = (f32x4)0.f;

  const int entA = (((lcol) + lrow * 4) & 15) + lrow * 16;

  auto loadE = [&](int t, float4& a0, float4& a1) {
    const float* p = Erow + t * KSTEP;
    a0 = *(const float4*)(p);
    a1 = *(const float4*)(p + 4);
  };
  auto loadF = [&](int t, float4& b0, float4& b1) {
    const float* p = F + (size_t)(v0 + t * KSTEP + 2 * fp) * NC + cb + fc0;
    b0 = *(const float4*)(p);
    b1 = *(const float4*)(p + NC);
  };

  auto stage = [&](int buf, float4 e0, float4 e1, float4 f0, float4 f1) {
    ushort* AHb = smem + buf * 16384;
    ushort* BHb = AHb + 8192;
    const float v[8] = {e0.x, e0.y, e0.z, e0.w, e1.x, e1.y, e1.z, e1.w};
    uint hiw[4], low[4];
#pragma unroll
    for (int i = 0; i < 4; i++) {
      float a = v[2 * i], c = v[2 * i + 1];
      ushort ha = f2bf(a), hc = f2bf(c);
      hiw[i] = (uint)ha | ((uint)hc << 16);
      low[i] = (uint)f2bf(a - bf2f(ha)) | ((uint)f2bf(c - bf2f(hc)) << 16);
    }
    *(uint4*)(AHb + ef * 512 + entE * 8)        = make_uint4(hiw[0], hiw[1], hiw[2], hiw[3]);
    *(uint4*)(AHb + 4096 + ef * 512 + entE * 8) = make_uint4(low[0], low[1], low[2], low[3]);

    const float* fa = (const float*)&f0;
    const float* fb = (const float*)&f1;
#pragma unroll
    for (int j = 0; j < 4; j++) {
      int ent = ((fclow + j + fcg) & 15) + fvg * 16;
      float a = fa[j], c = fb[j];
      ushort ha = f2bf(a), hc = f2bf(c);
      *(uint*)(BHb + fcg * 512 + ent * 8 + 2 * fsp) = (uint)ha | ((uint)hc << 16);
      *(uint*)(BHb + 4096 + fcg * 512 + ent * 8 + 2 * fsp) =
          (uint)f2bf(a - bf2f(ha)) | ((uint)f2bf(c - bf2f(hc)) << 16);
    }
  };

  auto domfma = [&](int buf) {
    const ushort* AHb = smem + buf * 16384;
    const ushort* BHb = AHb + 8192;
    bf16x8 bHf[2], bLf[2];
#pragma unroll
    for (int ni = 0; ni < 2; ni++) {
      int cg = wn * 2 + ni;
      int entB = ((lcol + cg) & 15) + lrow * 16;
      bHf[ni] = *(const bf16x8*)(BHb + cg * 512 + entB * 8);
      bLf[ni] = *(const bf16x8*)(BHb + 4096 + cg * 512 + entB * 8);
    }
#pragma unroll
    for (int fi = 0; fi < 4; fi++) {
      bf16x8 aH = *(const bf16x8*)(AHb + (wm * 4 + fi) * 512 + entA * 8);
      bf16x8 aL = *(const bf16x8*)(AHb + 4096 + (wm * 4 + fi) * 512 + entA * 8);
#pragma unroll
      for (int ni = 0; ni < 2; ni++) {
        acc[fi][ni] = __builtin_amdgcn_mfma_f32_16x16x32_bf16(aH, bHf[ni], acc[fi][ni], 0, 0, 0);
        acc[fi][ni] = __builtin_amdgcn_mfma_f32_16x16x32_bf16(aH, bLf[ni], acc[fi][ni], 0, 0, 0);
        acc[fi][ni] = __builtin_amdgcn_mfma_f32_16x16x32_bf16(aL, bHf[ni], acc[fi][ni], 0, 0, 0);
      }
    }
  };

  // ---- pipeline prologue ----
  float4 eA0, eA1, fA0, fA1, eB0, eB1, fB0, fB1;
  loadE(0, eA0, eA1); loadF(0, fA0, fA1);
  stage(0, eA0, eA1, fA0, fA1);
  {
    const int t1 = (1 < nsteps) ? 1 : 0;
    loadE(t1, eB0, eB1); loadF(t1, fB0, fB1);
  }
  __syncthreads();

  // ---- main loop: ONE barrier per step ----
  for (int s = 0; s < nsteps; s++) {
    const int bufc = s & 1;
    if (s + 1 < nsteps) {
      if ((s & 1) == 0) stage(bufc ^ 1, eB0, eB1, fB0, fB1);
      else              stage(bufc ^ 1, eA0, eA1, fA0, fA1);
    }
    if (s + 2 < nsteps) {
      if ((s & 1) == 0) { loadE(s + 2, eA0, eA1); loadF(s + 2, fA0, fA1); }
      else              { loadE(s + 2, eB0, eB1); loadF(s + 2, fB0, fB1); }
    }
    domfma(bufc);
    __syncthreads();
  }

  // ---- epilogue: C/D layout col=lane&15, row=(lane>>4)*4+reg ----
#pragma unroll
  for (int fi = 0; fi < 4; fi++) {
#pragma unroll
    for (int ni = 0; ni < 2; ni++) {
      const float* av = (const float*)&acc[fi][ni];
#pragma unroll
      for (int q = 0; q < 4; q++) {
        int row = wm * 64 + fi * 16 + lrow * 4 + q;
        int col = cb + wn * 32 + ni * 16 + lcol;
        if (MODE == 0) {
          P[(((size_t)chunk * 16 + bs) * NK + row) * NC + col] = av[q];
        } else {
          atomicAdd(&Out[(size_t)row * NC + col], av[q]);
        }
      }
    }
  }
}

__global__ __launch_bounds__(256) void reduce_kernel(
    const float* __restrict__ P, float* __restrict__ AB)
{
  const int g = blockIdx.x * 256 + threadIdx.x;
  const int bsi = g >> 13;
  const int rem4 = g & 8191;
  const int side = bsi & 1, b = bsi >> 1;
  float4 s = make_float4(0.f, 0.f, 0.f, 0.f);
#pragma unroll
  for (int ch = 0; ch < CHUNKS; ch++) {
    float4 v = *(const float4*)(P + (((size_t)ch * 16 + bsi) * 8192 + rem4) * 4);
    s.x += v.x; s.y += v.y; s.z += v.z; s.w += v.w;
  }
  *(float4*)(AB + ((size_t)side * 262144 + (size_t)b * 8192 * 4 + (size_t)rem4 * 4)) = s;
}

// ---------------------------------------------------------------------------
// 2) Gram
// ---------------------------------------------------------------------------
__global__ __launch_bounds__(256) void gram_kernel(
    const float* __restrict__ A, const float* __restrict__ Bm,
    float* __restrict__ AAt, float* __restrict__ BAt)
{
  const int i0 = blockIdx.x * 8;
  const int b  = blockIdx.y;
  __shared__ float Xi[16][260];
  const float* __restrict__ Ab = A  + (size_t)b * NK * NC;
  const float* __restrict__ Bb = Bm + (size_t)b * NK * NC;
  const int tid = threadIdx.x;
  for (int idx = tid; idx < 16 * 64; idx += 256) {
    int row = idx >> 6, c4 = idx & 63;
    const float* src = (row < 8) ? (Ab + (size_t)(i0 + row) * NC)
                                 : (Bb + (size_t)(i0 + row - 8) * NC);
    *(float4*)&Xi[row][c4 * 4] = *(const float4*)(src + c4 * 4);
  }
  __syncthreads();
  const int j = tid & 127;
  const int m = tid >> 7;
  const float* __restrict__ Arow = Ab + (size_t)j * NC;
  float accv[8];
#pragma unroll
  for (int i = 0; i < 8; i++) accv[i] = 0.f;
  for (int c4 = 0; c4 < 64; c4++) {
    float4 a4 = *(const float4*)(Arow + c4 * 4);
#pragma unroll
    for (int i = 0; i < 8; i++) {
      float4 x4 = *(const float4*)&Xi[m * 8 + i][c4 * 4];
      accv[i] = fmaf(x4.x, a4.x, accv[i]);
      accv[i] = fmaf(x4.y, a4.y, accv[i]);
      accv[i] = fmaf(x4.z, a4.z, accv[i]);
      accv[i] = fmaf(x4.w, a4.w, accv[i]);
    }
  }
  float* Outp = (m ? BAt : AAt) + ((size_t)b * NK + i0) * NK + j;
#pragma unroll
  for (int i = 0; i < 8; i++) Outp[(size_t)i * NK] = accv[i];
}

// ---------------------------------------------------------------------------
// 3) Mask D
// ---------------------------------------------------------------------------
__global__ __launch_bounds__(256) void mask_kernel(
    const float* __restrict__ evx, const float* __restrict__ evy,
    float* __restrict__ Dm)
{
  const int b = blockIdx.x;
  const int tid = threadIdx.x;
  __shared__ float red[256];
  __shared__ float t1x[128], t2x[128], t1y[128], t2y[128];
  float v = (tid < 128) ? evx[b * 128 + tid] : evy[b * 128 + (tid - 128)];
  red[tid] = v;
  __syncthreads();
  for (int sft = 128; sft > 0; sft >>= 1) {
    if (tid < sft) red[tid] = fmaxf(red[tid], red[tid + sft]);
    __syncthreads();
  }
  const float inv_scale = 1.0f / red[0];
  if (tid < 128) {
    float e = evx[b * 128 + tid] * inv_scale;
    float g = sqrtf(e);
    float d = 1.f / (g * g + 1.f);
    t1x[tid] = g * d;  t2x[tid] = d;
  } else {
    int i = tid - 128;
    float e = evy[b * 128 + i] * inv_scale;
    float g = sqrtf(e);
    float d = 1.f / (g * g + 1.f);
    t1y[i] = g * d;  t2y[i] = d;
  }
  __syncthreads();
  float* __restrict__ Db = Dm + (size_t)b * NK * NK;
  for (int idx = tid; idx < NK * NK; idx += 256) {
    int i = idx >> 7, jj = idx & 127;
    float re = t1y[i] - t1x[jj];
    float im = t2y[i] - t2x[jj];
    Db[idx] = re * re + im * im;
  }
}

// ---------------------------------------------------------------------------
// 4) Blocked Gauss-Jordan inversion, W=8 panels, redundant per-thread panel
//    inverse. ALL register-array indices are compile-time constants.
// ---------------------------------------------------------------------------
__global__ __launch_bounds__(512) void invert_kernel(
    const float* __restrict__ AAt, float* __restrict__ Sinv)
{
  extern __shared__ float sh[];
  float* M = sh;                       // [128][132]
  float* R = sh + 128 * 132;           // [8][132] pivot-row snapshot
  const int b = blockIdx.x;
  const int tid = threadIdx.x;
  const float* __restrict__ Sb = AAt + (size_t)b * NK * NK;
  for (int idx = tid; idx < NK * NK; idx += 512) {
    M[(idx >> 7) * 132 + (idx & 127)] = Sb[idx];
  }
  __syncthreads();
  const int r = tid & 127;
  const int h = tid >> 7;
  const int c0 = h * 32;

  for (int p = 0; p < 16; p++) {
    const int J0 = p * 8;
    const bool inJ = (r >= J0) && (r < J0 + 8);
    const int i0 = r - J0;             // row-in-panel (valid only when inJ)

    // ---- phase A (reads M only): redundant G8 = inv(M[J,J]) in registers ---
    float g[8][8];
#pragma unroll
    for (int i = 0; i < 8; i++)
#pragma unroll
      for (int j = 0; j < 8; j++) g[i][j] = M[(J0 + i) * 132 + J0 + j];

#pragma unroll
    for (int j = 0; j < 8; j++) {
      const float invd = 1.f / g[j][j];
#pragma unroll
      for (int i = 0; i < 8; i++) {
        if (i == j) continue;
        const float f = g[i][j] * invd;
#pragma unroll
        for (int c = 0; c < 8; c++) {
          if (c == j) continue;
          g[i][c] = fmaf(-f, g[j][c], g[i][c]);
        }
        g[i][j] = -f;
      }
#pragma unroll
      for (int c = 0; c < 8; c++) {
        if (c == j) continue;
        g[j][c] *= invd;
      }
      g[j][j] = invd;
    }

    // coupling factors for my row — static indices only
    float c8[8];
    if (inJ) {
#pragma unroll
      for (int q = 0; q < 8; q++) {
        float v = 0.f;
#pragma unroll
        for (int i = 0; i < 8; i++)
          if (i0 == i) v = g[i][q];            // static index, runtime select
        c8[q] = ((i0 == q) ? 1.f : 0.f) - v;
      }
    } else {
      float mr8[8];
#pragma unroll
      for (int k = 0; k < 8; k++) mr8[k] = M[r * 132 + J0 + k];
#pragma unroll
      for (int q = 0; q < 8; q++) {
        float a = 0.f;
#pragma unroll
        for (int k = 0; k < 8; k++) a = fmaf(mr8[k], g[k][q], a);
        c8[q] = a;
      }
    }

    // R snapshot of pivot rows (reads M, writes R)
    if (inJ) {
#pragma unroll
      for (int i = 0; i < 8; i++)
        *(float4*)&R[i0 * 132 + c0 + i * 4] = *(const float4*)&M[r * 132 + c0 + i * 4];
    }
    __syncthreads();

    // ---- phase C (writes M): Schur update on my exclusive slab ----
    float4 m[8];
#pragma unroll
    for (int i = 0; i < 8; i++) m[i] = *(const float4*)&M[r * 132 + c0 + i * 4];
#pragma unroll
    for (int k = 0; k < 8; k++) {
      const float f = c8[k];
#pragma unroll
      for (int i = 0; i < 8; i++) {
        float4 rv = *(const float4*)&R[k * 132 + c0 + i * 4];
        m[i].x = fmaf(-f, rv.x, m[i].x);
        m[i].y = fmaf(-f, rv.y, m[i].y);
        m[i].z = fmaf(-f, rv.z, m[i].z);
        m[i].w = fmaf(-f, rv.w, m[i].w);
      }
    }
    // panel columns get the closed form: -c8 (+I on pivot rows).
    {
      const bool panelH = (h == (J0 >> 5));
      const int q4 = (J0 & 31) >> 2;           // first float4 slot in slab
      float sp[8];
#pragma unroll
      for (int q = 0; q < 8; q++)
        sp[q] = -c8[q] + ((inJ && i0 == q) ? 1.f : 0.f);
      const float4 lo = make_float4(sp[0], sp[1], sp[2], sp[3]);
      const float4 hi = make_float4(sp[4], sp[5], sp[6], sp[7]);
#pragma unroll
      for (int i = 0; i < 8; i++) {
        if (panelH && i == q4)     m[i] = lo;
        if (panelH && i == q4 + 1) m[i] = hi;
      }
    }
#pragma unroll
    for (int i = 0; i < 8; i++) *(float4*)&M[r * 132 + c0 + i * 4] = m[i];
    __syncthreads();
  }

  float* __restrict__ Ob = Sinv + (size_t)b * NK * NK;
  for (int idx = tid; idx < NK * NK; idx += 512) {
    Ob[idx] = M[(idx >> 7) * 132 + (idx & 127)];
  }
}

// ---------------------------------------------------------------------------
// 4b) Newton-Schulz refinement: X <- X(2I - S*X). Load-bearing: squares the
//     inverse residual of the blocked-GJ result (round-9 A/B: removing it
//     regressed absmax 0.00195 -> 0.096).
// ---------------------------------------------------------------------------
__global__ __launch_bounds__(256) void ns_kernel(
    const float* __restrict__ AAt, float* __restrict__ Sinv)
{
  extern __shared__ float sh[];
  float* S_ = sh;               // [128][132], later holds W = 2I - S*X
  float* X_ = sh + 128 * 132;   // [128][132]
  const int b = blockIdx.x;
  const int tid = threadIdx.x;
  const float* __restrict__ Sg = AAt  + (size_t)b * NK * NK;
  float* __restrict__ Xg       = Sinv + (size_t)b * NK * NK;
  for (int idx = tid; idx < NK * NK; idx += 256) {
    int rr = idx >> 7, cc = idx & 127;
    S_[rr * 132 + cc] = Sg[idx];
    X_[rr * 132 + cc] = Xg[idx];
  }
  __syncthreads();
  const int i0 = (tid >> 4) * 8;
  const int j0 = (tid & 15) * 8;
  float w[8][8];
#pragma unroll
  for (int u = 0; u < 8; u++)
#pragma unroll
    for (int v = 0; v < 8; v++) w[u][v] = 0.f;
  for (int c = 0; c < NK; c++) {
    float sv[8], xv[8];
#pragma unroll
    for (int u = 0; u < 8; u++) sv[u] = S_[(i0 + u) * 132 + c];
#pragma unroll
    for (int v = 0; v < 8; v++) xv[v] = X_[c * 132 + j0 + v];
#pragma unroll
    for (int u = 0; u < 8; u++)
#pragma unroll
      for (int v = 0; v < 8; v++) w[u][v] = fmaf(sv[u], xv[v], w[u][v]);
  }
  __syncthreads();
#pragma unroll
  for (int u = 0; u < 8; u++)
#pragma unroll
    for (int v = 0; v < 8; v++) {
      float val = -w[u][v];
      if (i0 + u == j0 + v) val += 2.f;
      S_[(i0 + u) * 132 + j0 + v] = val;     // S_ now holds W
    }
  __syncthreads();
#pragma unroll
  for (int u = 0; u < 8; u++)
#pragma unroll
    for (int v = 0; v < 8; v++) w[u][v] = 0.f;
  for (int c = 0; c < NK; c++) {
    float xv[8], wv[8];
#pragma unroll
    for (int u = 0; u < 8; u++) xv[u] = X_[(i0 + u) * 132 + c];
#pragma unroll
    for (int v = 0; v < 8; v++) wv[v] = S_[c * 132 + j0 + v];
#pragma unroll
    for (int u = 0; u < 8; u++)
#pragma unroll
      for (int v = 0; v < 8; v++) w[u][v] = fmaf(xv[u], wv[v], w[u][v]);
  }
#pragma unroll
  for (int u = 0; u < 8; u++)
#pragma unroll
    for (int v = 0; v < 8; v++)
      Xg[(size_t)(i0 + u) * NK + j0 + v] = w[u][v];
}

// ---------------------------------------------------------------------------
// 5) Solve via Neumann fixed point (2 iterations).
// ---------------------------------------------------------------------------
__global__ __launch_bounds__(256) void solve_kernel(
    const float* __restrict__ Sinv, const float* __restrict__ BAt,
    const float* __restrict__ Dm, float* __restrict__ Cxy)
{
  extern __shared__ float sh[];
  float* SinvS = sh;               // [128][132]
  float* ZS    = sh + 128 * 132;   // [128][133]
  const int b = blockIdx.x;
  const int tid = threadIdx.x;
  const float* __restrict__ Sb = Sinv + (size_t)b * NK * NK;
  const float* __restrict__ Rb = BAt  + (size_t)b * NK * NK;
  const float* __restrict__ Db = Dm   + (size_t)b * NK * NK;
  for (int idx = tid; idx < NK * NK; idx += 256) {
    int r = idx >> 7, c = idx & 127;
    SinvS[r * 132 + c] = Sb[idx];
    ZS[r * 133 + c]    = Rb[idx];
  }
  __syncthreads();
  const int i0 = (tid >> 4) * 8;
  const int r0 = (tid & 15) * 8;
  float Y[8][8], X[8][8];
#pragma unroll
  for (int u = 0; u < 8; u++)
#pragma unroll
    for (int v = 0; v < 8; v++) Y[u][v] = 0.f;

  for (int c = 0; c < NK; c++) {
    float4 s0 = *(const float4*)&SinvS[c * 132 + r0];
    float4 s1 = *(const float4*)&SinvS[c * 132 + r0 + 4];
#pragma unroll
    for (int u = 0; u < 8; u++) {
      float z = ZS[(i0 + u) * 133 + c];
      Y[u][0] = fmaf(z, s0.x, Y[u][0]);
      Y[u][1] = fmaf(z, s0.y, Y[u][1]);
      Y[u][2] = fmaf(z, s0.z, Y[u][2]);
      Y[u][3] = fmaf(z, s0.w, Y[u][3]);
      Y[u][4] = fmaf(z, s1.x, Y[u][4]);
      Y[u][5] = fmaf(z, s1.y, Y[u][5]);
      Y[u][6] = fmaf(z, s1.z, Y[u][6]);
      Y[u][7] = fmaf(z, s1.w, Y[u][7]);
    }
  }
#pragma unroll
  for (int u = 0; u < 8; u++)
#pragma unroll
    for (int v = 0; v < 8; v++) X[u][v] = Y[u][v];

  for (int it = 0; it < 2; it++) {
    __syncthreads();
#pragma unroll
    for (int u = 0; u < 8; u++) {
      const float* drow = Db + (size_t)(i0 + u) * NK + r0;
      float* zrow = ZS + (i0 + u) * 133 + r0;
#pragma unroll
      for (int v = 0; v < 8; v++) zrow[v] = LMBDA * drow[v] * X[u][v];
    }
    __syncthreads();
#pragma unroll
    for (int u = 0; u < 8; u++)
#pragma unroll
      for (int v = 0; v < 8; v++) X[u][v] = Y[u][v];
    for (int c = 0; c < NK; c++) {
      float4 s0 = *(const float4*)&SinvS[c * 132 + r0];
      float4 s1 = *(const float4*)&SinvS[c * 132 + r0 + 4];
#pragma unroll
      for (int u = 0; u < 8; u++) {
        float z = ZS[(i0 + u) * 133 + c];
        X[u][0] = fmaf(-z, s0.x, X[u][0]);
        X[u][1] = fmaf(-z, s0.y, X[u][1]);
        X[u][2] = fmaf(-z, s0.z, X[u][2]);
        X[u][3] = fmaf(-z, s0.w, X[u][3]);
        X[u][4] = fmaf(-z, s1.x, X[u][4]);
        X[u][5] = fmaf(-z, s1.y, X[u][5]);
        X[u][6] = fmaf(-z, s1.z, X[u][6]);
        X[u][7] = fmaf(-z, s1.w, X[u][7]);
      }
    }
  }
  float* __restrict__ Ob = Cxy + ((size_t)b * NK + i0) * NK + r0;
#pragma unroll
  for (int u = 0; u < 8; u++) {
    float4 o0 = make_float4(X[u][0], X[u][1], X[u][2], X[u][3]);
    float4 o1 = make_float4(X[u][4], X[u][5], X[u][6], X[u][7]);
    *(float4*)(Ob + (size_t)u * NK)     = o0;
    *(float4*)(Ob + (size_t)u * NK + 4) = o1;
  }
}

} // anonymous namespace

extern "C" void kernel_launch(void* const* d_in, const int* in_sizes, int n_in,
                              void* d_out, int out_size, void* d_ws, size_t ws_size,
                              hipStream_t stream) {
  (void)in_sizes; (void)n_in; (void)out_size;
  const float* feat_x  = (const float*)d_in[0];
  const float* feat_y  = (const float*)d_in[1];
  const float* evals_x = (const float*)d_in[2];
  const float* evals_y = (const float*)d_in[3];
  const float* etx     = (const float*)d_in[4];
  const float* ety     = (const float*)d_in[5];
  float* out = (float*)d_out;
  float* ws  = (float*)d_ws;

  float* A    = ws;
  float* Bm   = ws + 262144;
  float* AAt  = ws + 524288;
  float* BAt  = ws + 655360;
  float* Dm   = ws + 786432;
  float* Sinv = ws + 917504;
  float* P    = ws + 1048576;

  const bool use_partial = ws_size >= (size_t)(1048576 + 8388608) * 4;

  constexpr int PROJ_LDS = 2 * 16384 * 2;                   // 65536 B (2 bufs)
  constexpr int INV_LDS = (128 * 132 + 8 * 132) * 4;        // 71808 B
  constexpr int NS_LDS  = (2 * 128 * 132) * 4;              // 135168 B
  hipFuncSetAttribute((const void*)proj_mfma<0>,
                      hipFuncAttributeMaxDynamicSharedMemorySize, PROJ_LDS);
  hipFuncSetAttribute((const void*)proj_mfma<1>,
                      hipFuncAttributeMaxDynamicSharedMemorySize, PROJ_LDS);
  hipFuncSetAttribute((const void*)invert_kernel,
                      hipFuncAttributeMaxDynamicSharedMemorySize, INV_LDS);
  hipFuncSetAttribute((const void*)ns_kernel,
                      hipFuncAttributeMaxDynamicSharedMemorySize, NS_LDS);
  hipFuncSetAttribute((const void*)solve_kernel,
                      hipFuncAttributeMaxDynamicSharedMemorySize, (128 * 132 + 128 * 133) * 4);

  if (use_partial) {
    proj_mfma<0><<<dim3(CHUNKS, 2, 16), 512, PROJ_LDS, stream>>>(etx, feat_x, ety, feat_y, A, Bm, P);
    reduce_kernel<<<dim3(512), 256, 0, stream>>>(P, ws);
  } else {
    hipMemsetAsync(A, 0, (size_t)524288 * sizeof(float), stream);
    proj_mfma<1><<<dim3(CHUNKS, 2, 16), 512, PROJ_LDS, stream>>>(etx, feat_x, ety, feat_y, A, Bm, P);
  }
  gram_kernel<<<dim3(16, 8), 256, 0, stream>>>(A, Bm, AAt, BAt);
  mask_kernel<<<dim3(8), 256, 0, stream>>>(evals_x, evals_y, Dm);
  invert_kernel<<<dim3(8), 512, INV_LDS, stream>>>(AAt, Sinv);
  ns_kernel<<<dim3(8), 256, NS_LDS, stream>>>(AAt, Sinv);
  ns_kernel<<<dim3(8), 256, NS_LDS, stream>>>(AAt, Sinv);
  solve_kernel<<<dim3(8), 256, (128 * 132 + 128 * 133) * 4, stream>>>(Sinv, BAt, Dm, out);
}

// Round 11
// 267.236 us; speedup vs baseline: 3.7622x; 1.3315x over previous
//
#include <hip/hip_runtime.h>
#include <hip/hip_bf16.h>

namespace {

constexpr int NB = 8;
constexpr int NV = 20000;
constexpr int NC = 256;
constexpr int NK = 128;
constexpr float LMBDA = 100.0f;
constexpr int KSTEP = 32;
constexpr int CHUNKS = 16;      // v-chunks; chunk 0 gets 40 steps, rest 39

typedef __attribute__((ext_vector_type(8))) short bf16x8;
typedef __attribute__((ext_vector_type(4))) float f32x4;

// HW packed conversion: low16 = bf16(a), high16 = bf16(c); RTNE (same as the
// previous manual integer rounding -> bit-identical on finite inputs).
__device__ __forceinline__ uint cvtpk(float a, float c) {
  uint r;
  asm("v_cvt_pk_bf16_f32 %0, %1, %2" : "=v"(r) : "v"(a), "v"(c));
  return r;
}

// ---------------------------------------------------------------------------
// 1) Spectral projection via split-bf16 MFMA (hi*hi + hi*lo + lo*hi).
//    Double-buffered LDS (2 x 32 KB), ONE barrier per K-step.
//    Conversion now uses v_cvt_pk_bf16_f32 (6 instr/pair vs ~25 manual).
// ---------------------------------------------------------------------------
template <int MODE>
__global__ __launch_bounds__(512, 4) void proj_mfma(
    const float* __restrict__ Ex, const float* __restrict__ Fx,
    const float* __restrict__ Ey, const float* __restrict__ Fy,
    float* __restrict__ A, float* __restrict__ Bm, float* __restrict__ P)
{
  extern __shared__ ushort smem[];         // 2 bufs x (AH 8192 + BH 8192) ushorts

  const int chunk = blockIdx.x;            // 0..15
  const int ct    = blockIdx.y;            // 0..1 (c half)
  const int bs    = blockIdx.z;            // b*2+side
  const int b     = bs >> 1;
  const int side  = bs & 1;
  const float* __restrict__ E = (side ? Ey : Ex) + (size_t)b * NK * NV;
  const float* __restrict__ F = (side ? Fy : Fx) + (size_t)b * NV * NC;
  float* __restrict__ Out = (side ? Bm : A) + (size_t)b * NK * NC;
  const int cb = ct * 128;

  const int start = chunk * 39 + (chunk > 0 ? 1 : 0);
  const int nsteps = 39 + (chunk == 0 ? 1 : 0);
  const int v0 = start * KSTEP;

  const int tid  = threadIdx.x;
  const int lane = tid & 63;
  const int w    = tid >> 6;
  const int wm   = w >> 2;       // 0..1 (64-row group)
  const int wn   = w & 3;        // 0..3 (32-col group)
  const int lrow = lane >> 4;    // 0..3
  const int lcol = lane & 15;

  const int ek  = tid >> 2;
  const int evg = tid & 3;
  const int ef  = ek >> 4;
  const int entE = (((ek & 15) + evg * 4) & 15) + evg * 16;
  const float* Erow = E + (size_t)ek * NV + v0 + evg * 8;

  const int fp  = tid & 15;
  const int fc0 = (tid >> 4) * 4;
  const int fcg = fc0 >> 4;
  const int fclow = fc0 & 15;
  const int fvg = fp >> 2;
  const int fsp = fp & 3;

  f32x4 acc[4][2];
#pragma unroll
  for (int fi = 0; fi < 4; fi++)
#pragma unroll
    for (int ni = 0; ni < 2; ni++) acc[fi][ni] = (f32x4)0.f;

  const int entA = (((lcol) + lrow * 4) & 15) + lrow * 16;

  auto loadE = [&](int t, float4& a0, float4& a1) {
    const float* p = Erow + t * KSTEP;
    a0 = *(const float4*)(p);
    a1 = *(const float4*)(p + 4);
  };
  auto loadF = [&](int t, float4& b0, float4& b1) {
    const float* p = F + (size_t)(v0 + t * KSTEP + 2 * fp) * NC + cb + fc0;
    b0 = *(const float4*)(p);
    b1 = *(const float4*)(p + NC);
  };

  auto stage = [&](int buf, float4 e0, float4 e1, float4 f0, float4 f1) {
    ushort* AHb = smem + buf * 16384;
    ushort* BHb = AHb + 8192;
    const float v[8] = {e0.x, e0.y, e0.z, e0.w, e1.x, e1.y, e1.z, e1.w};
    uint hiw[4], low[4];
#pragma unroll
    for (int i = 0; i < 4; i++) {
      float a = v[2 * i], c = v[2 * i + 1];
      uint h = cvtpk(a, c);
      low[i] = cvtpk(a - __uint_as_float(h << 16),
                     c - __uint_as_float(h & 0xffff0000u));
      hiw[i] = h;
    }
    *(uint4*)(AHb + ef * 512 + entE * 8)        = make_uint4(hiw[0], hiw[1], hiw[2], hiw[3]);
    *(uint4*)(AHb + 4096 + ef * 512 + entE * 8) = make_uint4(low[0], low[1], low[2], low[3]);

    const float* fa = (const float*)&f0;
    const float* fb = (const float*)&f1;
#pragma unroll
    for (int j = 0; j < 4; j++) {
      int ent = ((fclow + j + fcg) & 15) + fvg * 16;
      float a = fa[j], c = fb[j];
      uint h = cvtpk(a, c);
      uint l = cvtpk(a - __uint_as_float(h << 16),
                     c - __uint_as_float(h & 0xffff0000u));
      *(uint*)(BHb + fcg * 512 + ent * 8 + 2 * fsp) = h;
      *(uint*)(BHb + 4096 + fcg * 512 + ent * 8 + 2 * fsp) = l;
    }
  };

  auto domfma = [&](int buf) {
    const ushort* AHb = smem + buf * 16384;
    const ushort* BHb = AHb + 8192;
    bf16x8 bHf[2], bLf[2];
#pragma unroll
    for (int ni = 0; ni < 2; ni++) {
      int cg = wn * 2 + ni;
      int entB = ((lcol + cg) & 15) + lrow * 16;
      bHf[ni] = *(const bf16x8*)(BHb + cg * 512 + entB * 8);
      bLf[ni] = *(const bf16x8*)(BHb + 4096 + cg * 512 + entB * 8);
    }
#pragma unroll
    for (int fi = 0; fi < 4; fi++) {
      bf16x8 aH = *(const bf16x8*)(AHb + (wm * 4 + fi) * 512 + entA * 8);
      bf16x8 aL = *(const bf16x8*)(AHb + 4096 + (wm * 4 + fi) * 512 + entA * 8);
#pragma unroll
      for (int ni = 0; ni < 2; ni++) {
        acc[fi][ni] = __builtin_amdgcn_mfma_f32_16x16x32_bf16(aH, bHf[ni], acc[fi][ni], 0, 0, 0);
        acc[fi][ni] = __builtin_amdgcn_mfma_f32_16x16x32_bf16(aH, bLf[ni], acc[fi][ni], 0, 0, 0);
        acc[fi][ni] = __builtin_amdgcn_mfma_f32_16x16x32_bf16(aL, bHf[ni], acc[fi][ni], 0, 0, 0);
      }
    }
  };

  // ---- pipeline prologue ----
  float4 eA0, eA1, fA0, fA1, eB0, eB1, fB0, fB1;
  loadE(0, eA0, eA1); loadF(0, fA0, fA1);
  stage(0, eA0, eA1, fA0, fA1);
  {
    const int t1 = (1 < nsteps) ? 1 : 0;
    loadE(t1, eB0, eB1); loadF(t1, fB0, fB1);
  }
  __syncthreads();

  // ---- main loop: ONE barrier per step ----
  for (int s = 0; s < nsteps; s++) {
    const int bufc = s & 1;
    if (s + 1 < nsteps) {
      if ((s & 1) == 0) stage(bufc ^ 1, eB0, eB1, fB0, fB1);
      else              stage(bufc ^ 1, eA0, eA1, fA0, fA1);
    }
    if (s + 2 < nsteps) {
      if ((s & 1) == 0) { loadE(s + 2, eA0, eA1); loadF(s + 2, fA0, fA1); }
      else              { loadE(s + 2, eB0, eB1); loadF(s + 2, fB0, fB1); }
    }
    domfma(bufc);
    __syncthreads();
  }

  // ---- epilogue: C/D layout col=lane&15, row=(lane>>4)*4+reg ----
#pragma unroll
  for (int fi = 0; fi < 4; fi++) {
#pragma unroll
    for (int ni = 0; ni < 2; ni++) {
      const float* av = (const float*)&acc[fi][ni];
#pragma unroll
      for (int q = 0; q < 4; q++) {
        int row = wm * 64 + fi * 16 + lrow * 4 + q;
        int col = cb + wn * 32 + ni * 16 + lcol;
        if (MODE == 0) {
          P[(((size_t)chunk * 16 + bs) * NK + row) * NC + col] = av[q];
        } else {
          atomicAdd(&Out[(size_t)row * NC + col], av[q]);
        }
      }
    }
  }
}

__global__ __launch_bounds__(256) void reduce_kernel(
    const float* __restrict__ P, float* __restrict__ AB)
{
  const int g = blockIdx.x * 256 + threadIdx.x;
  const int bsi = g >> 13;
  const int rem4 = g & 8191;
  const int side = bsi & 1, b = bsi >> 1;
  float4 s = make_float4(0.f, 0.f, 0.f, 0.f);
#pragma unroll
  for (int ch = 0; ch < CHUNKS; ch++) {
    float4 v = *(const float4*)(P + (((size_t)ch * 16 + bsi) * 8192 + rem4) * 4);
    s.x += v.x; s.y += v.y; s.z += v.z; s.w += v.w;
  }
  *(float4*)(AB + ((size_t)side * 262144 + (size_t)b * 8192 * 4 + (size_t)rem4 * 4)) = s;
}

// ---------------------------------------------------------------------------
// 2) Gram
// ---------------------------------------------------------------------------
__global__ __launch_bounds__(256) void gram_kernel(
    const float* __restrict__ A, const float* __restrict__ Bm,
    float* __restrict__ AAt, float* __restrict__ BAt)
{
  const int i0 = blockIdx.x * 8;
  const int b  = blockIdx.y;
  __shared__ float Xi[16][260];
  const float* __restrict__ Ab = A  + (size_t)b * NK * NC;
  const float* __restrict__ Bb = Bm + (size_t)b * NK * NC;
  const int tid = threadIdx.x;
  for (int idx = tid; idx < 16 * 64; idx += 256) {
    int row = idx >> 6, c4 = idx & 63;
    const float* src = (row < 8) ? (Ab + (size_t)(i0 + row) * NC)
                                 : (Bb + (size_t)(i0 + row - 8) * NC);
    *(float4*)&Xi[row][c4 * 4] = *(const float4*)(src + c4 * 4);
  }
  __syncthreads();
  const int j = tid & 127;
  const int m = tid >> 7;
  const float* __restrict__ Arow = Ab + (size_t)j * NC;
  float accv[8];
#pragma unroll
  for (int i = 0; i < 8; i++) accv[i] = 0.f;
  for (int c4 = 0; c4 < 64; c4++) {
    float4 a4 = *(const float4*)(Arow + c4 * 4);
#pragma unroll
    for (int i = 0; i < 8; i++) {
      float4 x4 = *(const float4*)&Xi[m * 8 + i][c4 * 4];
      accv[i] = fmaf(x4.x, a4.x, accv[i]);
      accv[i] = fmaf(x4.y, a4.y, accv[i]);
      accv[i] = fmaf(x4.z, a4.z, accv[i]);
      accv[i] = fmaf(x4.w, a4.w, accv[i]);
    }
  }
  float* Outp = (m ? BAt : AAt) + ((size_t)b * NK + i0) * NK + j;
#pragma unroll
  for (int i = 0; i < 8; i++) Outp[(size_t)i * NK] = accv[i];
}

// ---------------------------------------------------------------------------
// 3) Mask D
// ---------------------------------------------------------------------------
__global__ __launch_bounds__(256) void mask_kernel(
    const float* __restrict__ evx, const float* __restrict__ evy,
    float* __restrict__ Dm)
{
  const int b = blockIdx.x;
  const int tid = threadIdx.x;
  __shared__ float red[256];
  __shared__ float t1x[128], t2x[128], t1y[128], t2y[128];
  float v = (tid < 128) ? evx[b * 128 + tid] : evy[b * 128 + (tid - 128)];
  red[tid] = v;
  __syncthreads();
  for (int sft = 128; sft > 0; sft >>= 1) {
    if (tid < sft) red[tid] = fmaxf(red[tid], red[tid + sft]);
    __syncthreads();
  }
  const float inv_scale = 1.0f / red[0];
  if (tid < 128) {
    float e = evx[b * 128 + tid] * inv_scale;
    float g = sqrtf(e);
    float d = 1.f / (g * g + 1.f);
    t1x[tid] = g * d;  t2x[tid] = d;
  } else {
    int i = tid - 128;
    float e = evy[b * 128 + i] * inv_scale;
    float g = sqrtf(e);
    float d = 1.f / (g * g + 1.f);
    t1y[i] = g * d;  t2y[i] = d;
  }
  __syncthreads();
  float* __restrict__ Db = Dm + (size_t)b * NK * NK;
  for (int idx = tid; idx < NK * NK; idx += 256) {
    int i = idx >> 7, jj = idx & 127;
    float re = t1y[i] - t1x[jj];
    float im = t2y[i] - t2x[jj];
    Db[idx] = re * re + im * im;
  }
}

// ---------------------------------------------------------------------------
// 4) Blocked Gauss-Jordan inversion, W=8 panels (unchanged, verified).
// ---------------------------------------------------------------------------
__global__ __launch_bounds__(512) void invert_kernel(
    const float* __restrict__ AAt, float* __restrict__ Sinv)
{
  extern __shared__ float sh[];
  float* M = sh;                       // [128][132]
  float* R = sh + 128 * 132;           // [8][132] pivot-row snapshot
  const int b = blockIdx.x;
  const int tid = threadIdx.x;
  const float* __restrict__ Sb = AAt + (size_t)b * NK * NK;
  for (int idx = tid; idx < NK * NK; idx += 512) {
    M[(idx >> 7) * 132 + (idx & 127)] = Sb[idx];
  }
  __syncthreads();
  const int r = tid & 127;
  const int h = tid >> 7;
  const int c0 = h * 32;

  for (int p = 0; p < 16; p++) {
    const int J0 = p * 8;
    const bool inJ = (r >= J0) && (r < J0 + 8);
    const int i0 = r - J0;

    float g[8][8];
#pragma unroll
    for (int i = 0; i < 8; i++)
#pragma unroll
      for (int j = 0; j < 8; j++) g[i][j] = M[(J0 + i) * 132 + J0 + j];

#pragma unroll
    for (int j = 0; j < 8; j++) {
      const float invd = 1.f / g[j][j];
#pragma unroll
      for (int i = 0; i < 8; i++) {
        if (i == j) continue;
        const float f = g[i][j] * invd;
#pragma unroll
        for (int c = 0; c < 8; c++) {
          if (c == j) continue;
          g[i][c] = fmaf(-f, g[j][c], g[i][c]);
        }
        g[i][j] = -f;
      }
#pragma unroll
      for (int c = 0; c < 8; c++) {
        if (c == j) continue;
        g[j][c] *= invd;
      }
      g[j][j] = invd;
    }

    float c8[8];
    if (inJ) {
#pragma unroll
      for (int q = 0; q < 8; q++) {
        float v = 0.f;
#pragma unroll
        for (int i = 0; i < 8; i++)
          if (i0 == i) v = g[i][q];
        c8[q] = ((i0 == q) ? 1.f : 0.f) - v;
      }
    } else {
      float mr8[8];
#pragma unroll
      for (int k = 0; k < 8; k++) mr8[k] = M[r * 132 + J0 + k];
#pragma unroll
      for (int q = 0; q < 8; q++) {
        float a = 0.f;
#pragma unroll
        for (int k = 0; k < 8; k++) a = fmaf(mr8[k], g[k][q], a);
        c8[q] = a;
      }
    }

    if (inJ) {
#pragma unroll
      for (int i = 0; i < 8; i++)
        *(float4*)&R[i0 * 132 + c0 + i * 4] = *(const float4*)&M[r * 132 + c0 + i * 4];
    }
    __syncthreads();

    float4 m[8];
#pragma unroll
    for (int i = 0; i < 8; i++) m[i] = *(const float4*)&M[r * 132 + c0 + i * 4];
#pragma unroll
    for (int k = 0; k < 8; k++) {
      const float f = c8[k];
#pragma unroll
      for (int i = 0; i < 8; i++) {
        float4 rv = *(const float4*)&R[k * 132 + c0 + i * 4];
        m[i].x = fmaf(-f, rv.x, m[i].x);
        m[i].y = fmaf(-f, rv.y, m[i].y);
        m[i].z = fmaf(-f, rv.z, m[i].z);
        m[i].w = fmaf(-f, rv.w, m[i].w);
      }
    }
    {
      const bool panelH = (h == (J0 >> 5));
      const int q4 = (J0 & 31) >> 2;
      float sp[8];
#pragma unroll
      for (int q = 0; q < 8; q++)
        sp[q] = -c8[q] + ((inJ && i0 == q) ? 1.f : 0.f);
      const float4 lo = make_float4(sp[0], sp[1], sp[2], sp[3]);
      const float4 hi = make_float4(sp[4], sp[5], sp[6], sp[7]);
#pragma unroll
      for (int i = 0; i < 8; i++) {
        if (panelH && i == q4)     m[i] = lo;
        if (panelH && i == q4 + 1) m[i] = hi;
      }
    }
#pragma unroll
    for (int i = 0; i < 8; i++) *(float4*)&M[r * 132 + c0 + i * 4] = m[i];
    __syncthreads();
  }

  float* __restrict__ Ob = Sinv + (size_t)b * NK * NK;
  for (int idx = tid; idx < NK * NK; idx += 512) {
    Ob[idx] = M[(idx >> 7) * 132 + (idx & 127)];
  }
}

// ---------------------------------------------------------------------------
// 4b) Newton-Schulz, COLUMN-PARALLEL: grid (4 col-tiles, 8 b). Ping-pong
//     Xin -> Xout (no intra-launch races). Same accumulation order as the
//     8-block version -> bit-identical. Uses AAt symmetry for row-reads.
// ---------------------------------------------------------------------------
__global__ __launch_bounds__(256) void ns_kernel(
    const float* __restrict__ AAt, const float* __restrict__ Xin,
    float* __restrict__ Xout)
{
  extern __shared__ float sh[];
  float* S_ = sh;                   // [128][132]
  float* X_ = sh + 128 * 132;       // [128][133]
  float* W_ = X_ + 128 * 133;       // [128][33] col-tile of W = 2I - S*X
  const int tile = blockIdx.x;      // 0..3
  const int b    = blockIdx.y;
  const int j0   = tile * 32;
  const int tid  = threadIdx.x;
  const float* __restrict__ Sg = AAt + (size_t)b * NK * NK;
  const float* __restrict__ Xg = Xin + (size_t)b * NK * NK;
  float* __restrict__ Og       = Xout + (size_t)b * NK * NK;
  for (int idx = tid; idx < NK * NK; idx += 256) {
    int rr = idx >> 7, cc = idx & 127;
    S_[rr * 132 + cc] = Sg[idx];
    X_[rr * 133 + cc] = Xg[idx];
  }
  __syncthreads();

  const int kg  = tid >> 4;         // 16 row-groups of 8
  const int jj2 = (tid & 15) * 2;   // 2 cols within tile

  // phase 1: W[k][jj] = 2I - sum_m S[k][m] X[m][j0+jj]   (S symmetric)
  float aw[8][2];
#pragma unroll
  for (int u = 0; u < 8; u++) { aw[u][0] = 0.f; aw[u][1] = 0.f; }
  for (int m = 0; m < NK; m++) {
    const float x0 = X_[m * 133 + j0 + jj2];
    const float x1 = X_[m * 133 + j0 + jj2 + 1];
    float4 s0 = *(const float4*)&S_[m * 132 + kg * 8];
    float4 s1 = *(const float4*)&S_[m * 132 + kg * 8 + 4];
    const float sv[8] = {s0.x, s0.y, s0.z, s0.w, s1.x, s1.y, s1.z, s1.w};
#pragma unroll
    for (int u = 0; u < 8; u++) {
      aw[u][0] = fmaf(sv[u], x0, aw[u][0]);
      aw[u][1] = fmaf(sv[u], x1, aw[u][1]);
    }
  }
#pragma unroll
  for (int u = 0; u < 8; u++) {
#pragma unroll
    for (int j = 0; j < 2; j++) {
      const int k = kg * 8 + u;
      float val = -aw[u][j];
      if (k == j0 + jj2 + j) val += 2.f;
      W_[k * 33 + jj2 + j] = val;
    }
  }
  __syncthreads();

  // phase 2: Xout[i][j0+jj] = sum_k X[i][k] W[k][jj]
  float ax[8][2];
#pragma unroll
  for (int u = 0; u < 8; u++) { ax[u][0] = 0.f; ax[u][1] = 0.f; }
  for (int k = 0; k < NK; k++) {
    const float w0 = W_[k * 33 + jj2];
    const float w1 = W_[k * 33 + jj2 + 1];
#pragma unroll
    for (int u = 0; u < 8; u++) {
      const float x = X_[(kg * 8 + u) * 133 + k];
      ax[u][0] = fmaf(x, w0, ax[u][0]);
      ax[u][1] = fmaf(x, w1, ax[u][1]);
    }
  }
#pragma unroll
  for (int u = 0; u < 8; u++) {
    Og[(size_t)(kg * 8 + u) * NK + j0 + jj2]     = ax[u][0];
    Og[(size_t)(kg * 8 + u) * NK + j0 + jj2 + 1] = ax[u][1];
  }
}

// ---------------------------------------------------------------------------
// 5) Solve via Neumann fixed point, ROW-PARALLEL: grid (4 row-tiles, 8 b).
//    Block owns 32 output rows; full Sinv in LDS; D read from global.
//    Same accumulation order -> bit-identical to the 8-block version.
// ---------------------------------------------------------------------------
__global__ __launch_bounds__(256) void solve_kernel(
    const float* __restrict__ Sinv, const float* __restrict__ BAt,
    const float* __restrict__ Dm, float* __restrict__ Cxy)
{
  extern __shared__ float sh[];
  float* SinvS = sh;               // [128][132]
  float* ZS    = sh + 128 * 132;   // [32][133]
  const int tile = blockIdx.x;     // 0..3
  const int b    = blockIdx.y;
  const int i0b  = tile * 32;
  const int tid  = threadIdx.x;
  const float* __restrict__ Sb = Sinv + (size_t)b * NK * NK;
  const float* __restrict__ Rb = BAt  + (size_t)b * NK * NK;
  const float* __restrict__ Db = Dm   + (size_t)b * NK * NK;
  for (int idx = tid; idx < NK * NK; idx += 256) {
    SinvS[(idx >> 7) * 132 + (idx & 127)] = Sb[idx];
  }
  for (int idx = tid; idx < 32 * NK; idx += 256) {
    int rr = idx >> 7, cc = idx & 127;
    ZS[rr * 133 + cc] = Rb[(size_t)(i0b + rr) * NK + cc];
  }
  __syncthreads();

  const int il = (tid >> 4) * 2;    // 2 local rows
  const int r0 = (tid & 15) * 8;    // 8 cols
  float Y[2][8], X[2][8];
#pragma unroll
  for (int u = 0; u < 2; u++)
#pragma unroll
    for (int v = 0; v < 8; v++) Y[u][v] = 0.f;

  for (int c = 0; c < NK; c++) {
    float4 s0 = *(const float4*)&SinvS[c * 132 + r0];
    float4 s1 = *(const float4*)&SinvS[c * 132 + r0 + 4];
#pragma unroll
    for (int u = 0; u < 2; u++) {
      float z = ZS[(il + u) * 133 + c];
      Y[u][0] = fmaf(z, s0.x, Y[u][0]);
      Y[u][1] = fmaf(z, s0.y, Y[u][1]);
      Y[u][2] = fmaf(z, s0.z, Y[u][2]);
      Y[u][3] = fmaf(z, s0.w, Y[u][3]);
      Y[u][4] = fmaf(z, s1.x, Y[u][4]);
      Y[u][5] = fmaf(z, s1.y, Y[u][5]);
      Y[u][6] = fmaf(z, s1.z, Y[u][6]);
      Y[u][7] = fmaf(z, s1.w, Y[u][7]);
    }
  }
#pragma unroll
  for (int u = 0; u < 2; u++)
#pragma unroll
    for (int v = 0; v < 8; v++) X[u][v] = Y[u][v];

  for (int it = 0; it < 2; it++) {
    __syncthreads();
#pragma unroll
    for (int u = 0; u < 2; u++) {
      const float* drow = Db + (size_t)(i0b + il + u) * NK + r0;
      float* zrow = ZS + (il + u) * 133 + r0;
#pragma unroll
      for (int v = 0; v < 8; v++) zrow[v] = LMBDA * drow[v] * X[u][v];
    }
    __syncthreads();
#pragma unroll
    for (int u = 0; u < 2; u++)
#pragma unroll
      for (int v = 0; v < 8; v++) X[u][v] = Y[u][v];
    for (int c = 0; c < NK; c++) {
      float4 s0 = *(const float4*)&SinvS[c * 132 + r0];
      float4 s1 = *(const float4*)&SinvS[c * 132 + r0 + 4];
#pragma unroll
      for (int u = 0; u < 2; u++) {
        float z = ZS[(il + u) * 133 + c];
        X[u][0] = fmaf(-z, s0.x, X[u][0]);
        X[u][1] = fmaf(-z, s0.y, X[u][1]);
        X[u][2] = fmaf(-z, s0.z, X[u][2]);
        X[u][3] = fmaf(-z, s0.w, X[u][3]);
        X[u][4] = fmaf(-z, s1.x, X[u][4]);
        X[u][5] = fmaf(-z, s1.y, X[u][5]);
        X[u][6] = fmaf(-z, s1.z, X[u][6]);
        X[u][7] = fmaf(-z, s1.w, X[u][7]);
      }
    }
  }
  float* __restrict__ Ob = Cxy + ((size_t)b * NK + i0b + il) * NK + r0;
#pragma unroll
  for (int u = 0; u < 2; u++) {
    float4 o0 = make_float4(X[u][0], X[u][1], X[u][2], X[u][3]);
    float4 o1 = make_float4(X[u][4], X[u][5], X[u][6], X[u][7]);
    *(float4*)(Ob + (size_t)u * NK)     = o0;
    *(float4*)(Ob + (size_t)u * NK + 4) = o1;
  }
}

} // anonymous namespace

extern "C" void kernel_launch(void* const* d_in, const int* in_sizes, int n_in,
                              void* d_out, int out_size, void* d_ws, size_t ws_size,
                              hipStream_t stream) {
  (void)in_sizes; (void)n_in; (void)out_size;
  const float* feat_x  = (const float*)d_in[0];
  const float* feat_y  = (const float*)d_in[1];
  const float* evals_x = (const float*)d_in[2];
  const float* evals_y = (const float*)d_in[3];
  const float* etx     = (const float*)d_in[4];
  const float* ety     = (const float*)d_in[5];
  float* out = (float*)d_out;
  float* ws  = (float*)d_ws;

  float* A    = ws;
  float* Bm   = ws + 262144;
  float* AAt  = ws + 524288;
  float* BAt  = ws + 655360;
  float* Dm   = ws + 786432;
  float* Sinv = ws + 917504;
  float* P    = ws + 1048576;
  float* Sinv2 = Bm;   // Bm region dead after gram_kernel; 131072 fits in 262144

  const bool use_partial = ws_size >= (size_t)(1048576 + 8388608) * 4;

  constexpr int PROJ_LDS  = 2 * 16384 * 2;                       // 65536 B
  constexpr int INV_LDS   = (128 * 132 + 8 * 132) * 4;           // 71808 B
  constexpr int NS_LDS    = (128 * 132 + 128 * 133 + 128 * 33) * 4;   // 152576 B
  constexpr int SOLVE_LDS = (128 * 132 + 32 * 133) * 4;          // 84608 B
  hipFuncSetAttribute((const void*)proj_mfma<0>,
                      hipFuncAttributeMaxDynamicSharedMemorySize, PROJ_LDS);
  hipFuncSetAttribute((const void*)proj_mfma<1>,
                      hipFuncAttributeMaxDynamicSharedMemorySize, PROJ_LDS);
  hipFuncSetAttribute((const void*)invert_kernel,
                      hipFuncAttributeMaxDynamicSharedMemorySize, INV_LDS);
  hipFuncSetAttribute((const void*)ns_kernel,
                      hipFuncAttributeMaxDynamicSharedMemorySize, NS_LDS);
  hipFuncSetAttribute((const void*)solve_kernel,
                      hipFuncAttributeMaxDynamicSharedMemorySize, SOLVE_LDS);

  if (use_partial) {
    proj_mfma<0><<<dim3(CHUNKS, 2, 16), 512, PROJ_LDS, stream>>>(etx, feat_x, ety, feat_y, A, Bm, P);
    reduce_kernel<<<dim3(512), 256, 0, stream>>>(P, ws);
  } else {
    hipMemsetAsync(A, 0, (size_t)524288 * sizeof(float), stream);
    proj_mfma<1><<<dim3(CHUNKS, 2, 16), 512, PROJ_LDS, stream>>>(etx, feat_x, ety, feat_y, A, Bm, P);
  }
  gram_kernel<<<dim3(16, 8), 256, 0, stream>>>(A, Bm, AAt, BAt);
  mask_kernel<<<dim3(8), 256, 0, stream>>>(evals_x, evals_y, Dm);
  invert_kernel<<<dim3(8), 512, INV_LDS, stream>>>(AAt, Sinv);
  ns_kernel<<<dim3(4, 8), 256, NS_LDS, stream>>>(AAt, Sinv, Sinv2);
  ns_kernel<<<dim3(4, 8), 256, NS_LDS, stream>>>(AAt, Sinv2, Sinv);
  solve_kernel<<<dim3(4, 8), 256, SOLVE_LDS, stream>>>(Sinv, BAt, Dm, out);
}